// Round 10
// baseline (1467.505 us; speedup 1.0000x reference)
//
#include <hip/hip_runtime.h>

// ---------------------------------------------------------------------------
// GraphSAGE GNN forward, MI355X round 10:
//  - attention: 1024 thr / 16 waves per block (occupancy 8->16 waves/CU)
//  - aggregation: half-wave per node, uint4 row gathers
// ---------------------------------------------------------------------------

#define N_TOT   65536
#define B_GR    128
#define NP_     512
#define E_TOT   524288
#define EPG     4096
#define DIN_    128
#define C_      256
#define C3_     768
#define H_      4

typedef unsigned int uint;
typedef unsigned short ushort;

// param pool element offsets (ushorts)
#define O_L0LW  0u
#define O_L0LB  32768u
#define O_L0RW  33024u
#define O_L0RES 65792u
#define O_LWL   98560u
#define O_LBL   295168u
#define O_LWR   295936u
#define O_GNW   492544u
#define O_GNB   493568u
#define O_GNA   494592u
#define O_AIW   495616u
#define O_AIB   692224u
#define O_AOW   692992u
#define O_AOB   758528u
#define O_LNW   758784u
#define O_LNB   759040u
#define O_PLW   759296u
#define O_PLB   955904u
#define TOTALP  956160u

typedef __attribute__((ext_vector_type(8))) short bf16x8_t;
typedef __attribute__((ext_vector_type(4))) float f32x4_t;

__device__ __forceinline__ float bf2f(ushort u){ union{uint i; float f;} v; v.i = ((uint)u) << 16; return v.f; }
__device__ __forceinline__ ushort f2bf(float f){
  union{float f; uint u;} v; v.f = f;
  uint u = v.u;
  u += 0x7fffu + ((u >> 16) & 1u);   // RNE
  return (ushort)(u >> 16);
}
__device__ __forceinline__ uint pack2(float a, float b){ return (uint)f2bf(a) | ((uint)f2bf(b) << 16); }
__device__ __forceinline__ float u2f_lo(uint u){ union{uint i; float f;} v; v.i = u << 16; return v.f; }
__device__ __forceinline__ float u2f_hi(uint u){ union{uint i; float f;} v; v.i = u & 0xffff0000u; return v.f; }
__device__ __forceinline__ float gelu_f(float x){ return 0.5f * x * (1.0f + erff(x * 0.70710678118654752440f)); }
__device__ __forceinline__ float wredsum(float v){
  #pragma unroll
  for (int off = 32; off; off >>= 1) v += __shfl_xor(v, off, 64);
  return v;
}

// ---------------------------------------------------------------------------
// dtype probe: gn_w[0]==1.0. f32 -> 0x3F800000 ; bf16 pair -> 0x3F803F80
__global__ void probe_dtype(const uint* __restrict__ gnw_raw, uint* __restrict__ flag){
  if (threadIdx.x == 0 && blockIdx.x == 0)
    *flag = (gnw_raw[0] == 0x3F800000u) ? 1u : 0u;   // 1 = f32 inputs
}

struct Seg { const void* p; uint ofs; };
struct CvtArgs { Seg s[19]; };

__global__ __launch_bounds__(256) void cvt_params(CvtArgs a, ushort* __restrict__ pb,
                                                  const uint* __restrict__ flag){
  uint gi = blockIdx.x * 256u + threadIdx.x;
  if (gi >= TOTALP) return;
  int lo = 0;
  #pragma unroll
  for (int s = 1; s < 18; ++s) if (gi >= a.s[s].ofs) lo = s;
  uint rel = gi - a.s[lo].ofs;
  pb[gi] = (*flag) ? f2bf(((const float*)a.s[lo].p)[rel]) : ((const ushort*)a.s[lo].p)[rel];
}

__global__ __launch_bounds__(256) void cvt_flat(const void* __restrict__ in, ushort* __restrict__ out,
                                                const uint* __restrict__ flag){
  uint i = blockIdx.x * 256u + threadIdx.x;
  out[i] = (*flag) ? f2bf(((const float*)in)[i]) : ((const ushort*)in)[i];
}

// ---------------------------------------------------------------------------
__global__ void deg_count(const int* __restrict__ dst, uint* __restrict__ deg){
  int e = blockIdx.x * 256 + threadIdx.x;
  atomicAdd(&deg[dst[e]], 1u);
}

// per-graph exclusive scan of deg (512 nodes) -> rowptr/cursor
__global__ __launch_bounds__(512) void scan_deg(const uint* __restrict__ deg,
    uint* __restrict__ rowptr, uint* __restrict__ cursor)
{
  __shared__ uint s[512];
  const int g = blockIdx.x, tid = threadIdx.x;
  uint v = deg[g * NP_ + tid];
  s[tid] = v;
  __syncthreads();
  #pragma unroll
  for (int off = 1; off < 512; off <<= 1) {
    uint t = (tid >= off) ? s[tid - off] : 0u;
    __syncthreads();
    s[tid] += t;
    __syncthreads();
  }
  uint p = g * EPG + (s[tid] - v);
  rowptr[g * NP_ + tid] = p;
  cursor[g * NP_ + tid] = p;
}

__global__ void scatter_edges(const int* __restrict__ src, const int* __restrict__ dst,
    uint* __restrict__ cursor, int* __restrict__ csr)
{
  int e = blockIdx.x * 256 + threadIdx.x;
  uint p = atomicAdd(&cursor[dst[e]], 1u);
  csr[p] = src[e];
}

// ---------------------------------------------------------------------------
// CSR mean-aggregation: half-wave (32 lanes) per node, full 512B row per load.
template<int D>
__global__ __launch_bounds__(256) void sage_agg_csr(const ushort* __restrict__ X,
    const int* __restrict__ csr, const uint* __restrict__ rowptr,
    const uint* __restrict__ deg, ushort* __restrict__ agg)
{
  constexpr int CPL = D / 32;    // 4 (D=128, uint2) or 8 (D=256, uint4)
  const int tid = threadIdx.x, lane = tid & 63, wave = tid >> 6;
  const int half = lane >> 5, l32 = lane & 31;
  const int n = blockIdx.x * 8 + wave * 2 + half;
  const uint start = rowptr[n];
  const uint dg = deg[n];
  const int co = l32 * CPL;
  float acc[CPL];
  #pragma unroll
  for (int k = 0; k < CPL; ++k) acc[k] = 0.0f;

  auto addrow = [&](int s) {
    const ushort* r = X + (size_t)s * D + co;
    if constexpr (CPL == 4) {
      uint2 u = *(const uint2*)r;
      acc[0] += u2f_lo(u.x); acc[1] += u2f_hi(u.x);
      acc[2] += u2f_lo(u.y); acc[3] += u2f_hi(u.y);
    } else {
      uint4 u = *(const uint4*)r;
      acc[0] += u2f_lo(u.x); acc[1] += u2f_hi(u.x);
      acc[2] += u2f_lo(u.y); acc[3] += u2f_hi(u.y);
      acc[4] += u2f_lo(u.z); acc[5] += u2f_hi(u.z);
      acc[6] += u2f_lo(u.w); acc[7] += u2f_hi(u.w);
    }
  };

  uint j = 0;
  for (; j + 4 <= dg; j += 4) {
    int s0 = csr[start + j],     s1 = csr[start + j + 1];
    int s2 = csr[start + j + 2], s3 = csr[start + j + 3];
    addrow(s0); addrow(s1); addrow(s2); addrow(s3);
  }
  for (; j < dg; ++j) addrow(csr[start + j]);

  float inv = 1.0f / (float)(dg < 1u ? 1u : dg);
  ushort* op = agg + (size_t)n * D + co;
  if constexpr (CPL == 4) {
    uint2 o; o.x = pack2(acc[0] * inv, acc[1] * inv);
    o.y = pack2(acc[2] * inv, acc[3] * inv);
    *(uint2*)op = o;
  } else {
    uint4 o;
    o.x = pack2(acc[0] * inv, acc[1] * inv);
    o.y = pack2(acc[2] * inv, acc[3] * inv);
    o.z = pack2(acc[4] * inv, acc[5] * inv);
    o.w = pack2(acc[6] * inv, acc[7] * inv);
    *(uint4*)op = o;
  }
}

// ---------------------------------------------------------------------------
// MFMA GEMM v3: 64x256 block, 4 waves, wave = 64x64. A-stream prefetched.
// RN=true: fused SAGE row-L2-normalize + GraphNorm moment atomics.
template<bool DUAL, bool RN>
__global__ __launch_bounds__(256, 4) void gemm_mfma(
    const ushort* __restrict__ A1, int lda1, const ushort* __restrict__ W1,
    const ushort* __restrict__ A2, int lda2, const ushort* __restrict__ W2,
    const ushort* __restrict__ bias, const ushort* addend,   // addend may alias out
    ushort* out, int K, int ldOut,
    float* __restrict__ m1, float* __restrict__ m2)
{
  __shared__ float Cs[4][32 * 68];
  __shared__ float SSq[32];
  const int lane = threadIdx.x & 63, wave = threadIdx.x >> 6;
  const int lr = lane & 15, quad = lane >> 4;
  const int m0 = blockIdx.x * 64;
  const int n0 = blockIdx.y * 256 + wave * 64;
  f32x4_t acc[4][4];
  #pragma unroll
  for (int rt = 0; rt < 4; ++rt)
    #pragma unroll
    for (int ct = 0; ct < 4; ++ct) acc[rt][ct] = (f32x4_t){0.f, 0.f, 0.f, 0.f};
  {
    const ushort* ap = A1 + (size_t)(m0 + lr) * lda1 + quad * 8;
    const ushort* wp = W1 + (size_t)(n0 + lr) * K + quad * 8;
    bf16x8_t a[4];
    #pragma unroll
    for (int rt = 0; rt < 4; ++rt) a[rt] = *(const bf16x8_t*)(ap + (size_t)(rt * 16) * lda1);
    for (int kb = 0; kb < K; kb += 32) {
      int kn = (kb + 32 < K) ? kb + 32 : kb;
      bf16x8_t b[4], an[4];
      #pragma unroll
      for (int ct = 0; ct < 4; ++ct) b[ct] = *(const bf16x8_t*)(wp + (size_t)(ct * 16) * K + kb);
      #pragma unroll
      for (int rt = 0; rt < 4; ++rt) an[rt] = *(const bf16x8_t*)(ap + (size_t)(rt * 16) * lda1 + kn);
      #pragma unroll
      for (int rt = 0; rt < 4; ++rt)
        #pragma unroll
        for (int ct = 0; ct < 4; ++ct)
          acc[rt][ct] = __builtin_amdgcn_mfma_f32_16x16x32_bf16(a[rt], b[ct], acc[rt][ct], 0, 0, 0);
      #pragma unroll
      for (int rt = 0; rt < 4; ++rt) a[rt] = an[rt];
    }
  }
  if constexpr (DUAL) {
    const ushort* ap = A2 + (size_t)(m0 + lr) * lda2 + quad * 8;
    const ushort* wp = W2 + (size_t)(n0 + lr) * K + quad * 8;
    bf16x8_t a[4];
    #pragma unroll
    for (int rt = 0; rt < 4; ++rt) a[rt] = *(const bf16x8_t*)(ap + (size_t)(rt * 16) * lda2);
    for (int kb = 0; kb < K; kb += 32) {
      int kn = (kb + 32 < K) ? kb + 32 : kb;
      bf16x8_t b[4], an[4];
      #pragma unroll
      for (int ct = 0; ct < 4; ++ct) b[ct] = *(const bf16x8_t*)(wp + (size_t)(ct * 16) * K + kb);
      #pragma unroll
      for (int rt = 0; rt < 4; ++rt) an[rt] = *(const bf16x8_t*)(ap + (size_t)(rt * 16) * lda2 + kn);
      #pragma unroll
      for (int rt = 0; rt < 4; ++rt)
        #pragma unroll
        for (int ct = 0; ct < 4; ++ct)
          acc[rt][ct] = __builtin_amdgcn_mfma_f32_16x16x32_bf16(a[rt], b[ct], acc[rt][ct], 0, 0, 0);
      #pragma unroll
      for (int rt = 0; rt < 4; ++rt) a[rt] = an[rt];
    }
  }
  // ---- epilogue ----
  const int cb = lr * 4;
  float bv[4] = {0.f, 0.f, 0.f, 0.f};
  if (bias) {
    #pragma unroll
    for (int j = 0; j < 4; ++j) bv[j] = bf2f(bias[n0 + cb + j]);
  }
  float* cs = &Cs[wave][0];
  float a1s[4] = {0.f, 0.f, 0.f, 0.f}, a2s[4] = {0.f, 0.f, 0.f, 0.f};
  #pragma unroll
  for (int round = 0; round < 2; ++round) {
    #pragma unroll
    for (int rt2 = 0; rt2 < 2; ++rt2) {
      int rt = round * 2 + rt2;
      #pragma unroll
      for (int ct = 0; ct < 4; ++ct)
        #pragma unroll
        for (int r = 0; r < 4; ++r) {
          float v = acc[rt][ct][r];
          if constexpr (RN) v += bias ? bf2f(bias[n0 + ct * 16 + lr]) : 0.0f;
          cs[(rt2 * 16 + quad * 4 + r) * 68 + ct * 16 + lr] = v;
        }
    }
    if constexpr (RN) { if (threadIdx.x < 32) SSq[threadIdx.x] = 0.0f; }
    __syncthreads();
    if constexpr (RN) {
      #pragma unroll
      for (int it = 0; it < 8; ++it) {
        int Lr = it * 4 + quad;
        float4 v = *(const float4*)(cs + Lr * 68 + cb);
        float ss = v.x*v.x + v.y*v.y + v.z*v.z + v.w*v.w;
        #pragma unroll
        for (int off = 1; off < 16; off <<= 1) ss += __shfl_xor(ss, off, 64);
        if (lr == 0) atomicAdd(&SSq[Lr], ss);
      }
      __syncthreads();
      #pragma unroll
      for (int it = 0; it < 8; ++it) {
        int Lr = it * 4 + quad;
        float inv = 1.0f / fmaxf(sqrtf(SSq[Lr]), 1e-12f);
        float4 v = *(const float4*)(cs + Lr * 68 + cb);
        float r0 = v.x * inv, r1 = v.y * inv, r2 = v.z * inv, r3 = v.w * inv;
        a1s[0] += r0; a1s[1] += r1; a1s[2] += r2; a1s[3] += r3;
        a2s[0] += r0*r0; a2s[1] += r1*r1; a2s[2] += r2*r2; a2s[3] += r3*r3;
        size_t ob = (size_t)(m0 + round * 32 + Lr) * ldOut + n0 + cb;
        uint2 o; o.x = pack2(r0, r1); o.y = pack2(r2, r3);
        *(uint2*)(out + ob) = o;
      }
    } else {
      #pragma unroll
      for (int it = 0; it < 8; ++it) {
        int Lr = it * 4 + quad;
        float4 v = *(const float4*)(cs + Lr * 68 + cb);
        int grow = m0 + round * 32 + Lr;
        size_t ob = (size_t)grow * ldOut + n0 + cb;
        float r0 = v.x + bv[0], r1 = v.y + bv[1], r2 = v.z + bv[2], r3 = v.w + bv[3];
        if (addend) {
          uint2 ad = *(const uint2*)(addend + ob);
          r0 += u2f_lo(ad.x); r1 += u2f_hi(ad.x);
          r2 += u2f_lo(ad.y); r3 += u2f_hi(ad.y);
        }
        uint2 o; o.x = pack2(r0, r1); o.y = pack2(r2, r3);
        *(uint2*)(out + ob) = o;
      }
    }
    __syncthreads();
  }
  if constexpr (RN) {
    const int g = m0 >> 9;
    #pragma unroll
    for (int k = 0; k < 4; ++k) {
      atomicAdd(&m1[g*C_ + n0 + cb + k], a1s[k]);
      atomicAdd(&m2[g*C_ + n0 + cb + k], a2s[k]);
    }
  }
}

// GraphNorm + GELU + residual. m1/m2 hold SUMS over 512 nodes.
__global__ __launch_bounds__(256) void gn_gelu_add(const ushort* __restrict__ h,
    const ushort* res,
    const float* __restrict__ m1, const float* __restrict__ m2,
    const ushort* __restrict__ gw, const ushort* __restrict__ gb, const ushort* __restrict__ ga,
    ushort* out)
{
  size_t b4 = ((size_t)blockIdx.x * 256 + threadIdx.x) * 4;
  int c = (int)(b4 & (C_ - 1));
  int n = (int)(b4 >> 8);
  int g = n >> 9;
  uint2 hv = *(const uint2*)(h + b4);
  uint2 rv = *(const uint2*)(res + b4);
  float hh[4] = {u2f_lo(hv.x), u2f_hi(hv.x), u2f_lo(hv.y), u2f_hi(hv.y)};
  float rr[4] = {u2f_lo(rv.x), u2f_hi(rv.x), u2f_lo(rv.y), u2f_hi(rv.y)};
  float oo[4];
  #pragma unroll
  for (int j = 0; j < 4; ++j) {
    int cc = c + j;
    float a  = bf2f(ga[cc]);
    float mm = m1[g*C_ + cc] * (1.0f / 512.0f);
    float q2 = m2[g*C_ + cc] * (1.0f / 512.0f);
    float var = q2 - a * (2.0f - a) * mm * mm;
    float xo = hh[j] - a * mm;
    float y = bf2f(gw[cc]) * xo * rsqrtf(var + 1e-5f) + bf2f(gb[cc]);
    oo[j] = gelu_f(y) + rr[j];
  }
  uint2 ov; ov.x = pack2(oo[0], oo[1]); ov.y = pack2(oo[2], oo[3]);
  *(uint2*)(out + b4) = ov;
}

// ---------------------------------------------------------------------------
// MFMA attention: one block (1024 thr = 16 waves) per (graph, head).
// LDS 160,768 B (<= 160 KiB): Ks 73728 + Vt 66560 + Pw 20480.
#define KS_P 72
#define VT_P 520
#define PW_P 40
__global__ __launch_bounds__(1024, 1) void attn_kernel(ushort* __restrict__ qkv)
{
  __shared__ ushort Ks[NP_ * KS_P];
  __shared__ ushort Vt[64 * VT_P];
  __shared__ ushort Pw[16][16 * PW_P];
  const int bid = blockIdx.x;
  const int g = bid >> 2, h = bid & 3;
  const int tid = threadIdx.x, lane = tid & 63, wave = tid >> 6;
  const int lr = lane & 15, quad = lane >> 4;
  const size_t base = (size_t)g * NP_ * C3_;
  const int qoff = h * 64, koff = C_ + h * 64, voff = 2 * C_ + h * 64;
  for (int idx = tid; idx < NP_ * 64; idx += 1024) {
    int j = idx >> 6, c = idx & 63;
    const ushort* row = qkv + base + (size_t)j * C3_;
    Ks[j * KS_P + c] = row[koff + c];
    Vt[c * VT_P + j] = row[voff + c];
  }
  __syncthreads();
  ushort* pw = &Pw[wave][0];
  const int q0 = wave * 32;
  for (int qt = 0; qt < 2; ++qt) {
    const int qr = q0 + qt * 16;
    const ushort* qp = qkv + base + (size_t)(qr + lr) * C3_ + qoff + quad * 8;
    bf16x8_t qa0 = *(const bf16x8_t*)(qp);
    bf16x8_t qa1 = *(const bf16x8_t*)(qp + 32);
    f32x4_t s[32];
    #pragma unroll
    for (int t = 0; t < 32; ++t) {
      const ushort* kp = Ks + (size_t)(t * 16 + lr) * KS_P + quad * 8;
      bf16x8_t b0 = *(const bf16x8_t*)(kp);
      bf16x8_t b1 = *(const bf16x8_t*)(kp + 32);
      f32x4_t a = (f32x4_t){0.f, 0.f, 0.f, 0.f};
      a = __builtin_amdgcn_mfma_f32_16x16x32_bf16(qa0, b0, a, 0, 0, 0);
      a = __builtin_amdgcn_mfma_f32_16x16x32_bf16(qa1, b1, a, 0, 0, 0);
      s[t] = a;
    }
    float invv[4];
    #pragma unroll
    for (int r = 0; r < 4; ++r) {
      float m = s[0][r];
      #pragma unroll
      for (int t = 1; t < 32; ++t) m = fmaxf(m, s[t][r]);
      #pragma unroll
      for (int off = 8; off; off >>= 1) m = fmaxf(m, __shfl_xor(m, off, 64));
      float sm = 0.0f;
      #pragma unroll
      for (int t = 0; t < 32; ++t) {
        float e = __expf((s[t][r] - m) * 0.125f);
        s[t][r] = e; sm += e;
      }
      #pragma unroll
      for (int off = 8; off; off >>= 1) sm += __shfl_xor(sm, off, 64);
      invv[r] = 1.0f / sm;
    }
    f32x4_t o[4];
    #pragma unroll
    for (int t = 0; t < 4; ++t) o[t] = (f32x4_t){0.f, 0.f, 0.f, 0.f};
    for (int kc = 0; kc < 16; ++kc) {
      #pragma unroll
      for (int half = 0; half < 2; ++half) {
        int t = kc * 2 + half;
        #pragma unroll
        for (int r = 0; r < 4; ++r)
          pw[(quad * 4 + r) * PW_P + half * 16 + lr] = f2bf(s[t][r] * invv[r]);
      }
      __threadfence_block();
      bf16x8_t pa = *(const bf16x8_t*)(pw + lr * PW_P + quad * 8);
      #pragma unroll
      for (int nt = 0; nt < 4; ++nt) {
        const ushort* vp = Vt + (size_t)(nt * 16 + lr) * VT_P + kc * 32 + quad * 8;
        bf16x8_t b = *(const bf16x8_t*)(vp);
        o[nt] = __builtin_amdgcn_mfma_f32_16x16x32_bf16(pa, b, o[nt], 0, 0, 0);
      }
    }
    #pragma unroll
    for (int nt = 0; nt < 4; ++nt)
      #pragma unroll
      for (int r = 0; r < 4; ++r)
        qkv[base + (size_t)(qr + quad * 4 + r) * C3_ + koff + nt * 16 + lr] =
            f2bf(o[nt][r]);
  }
}

// ---------------------------------------------------------------------------
// Graph-LN: partial sums (grid 128x8) -> atomics; finalize converts to mu/var.
__global__ __launch_bounds__(256) void ln_part(const ushort* __restrict__ x2, float* __restrict__ st)
{
  __shared__ float a1[4], a2[4];
  const int g = blockIdx.x, sl = blockIdx.y;
  const int tid = threadIdx.x, lane = tid & 63, wave = tid >> 6;
  const ushort* p = x2 + ((size_t)g * NP_ + sl * 64) * C_;
  float s = 0.0f, q = 0.0f;
  for (int i = tid; i < 64 * C_; i += 256) { float v = bf2f(p[i]); s += v; q += v * v; }
  s = wredsum(s); q = wredsum(q);
  if (lane == 0) { a1[wave] = s; a2[wave] = q; }
  __syncthreads();
  if (tid == 0) {
    atomicAdd(&st[g * 2],     a1[0] + a1[1] + a1[2] + a1[3]);
    atomicAdd(&st[g * 2 + 1], a2[0] + a2[1] + a2[2] + a2[3]);
  }
}

__global__ void ln_finalize(float* __restrict__ st)
{
  int g = threadIdx.x;
  float S = st[g * 2], Q = st[g * 2 + 1];
  float mu = S * (1.0f / (NP_ * C_));
  float var = Q * (1.0f / (NP_ * C_)) - mu * mu;
  st[g * 2] = mu; st[g * 2 + 1] = var;
}

__global__ __launch_bounds__(256) void ln_gelu(const ushort* __restrict__ x2, const float* __restrict__ st,
    const ushort* __restrict__ lw, const ushort* __restrict__ lb, ushort* __restrict__ x3)
{
  size_t b4 = ((size_t)blockIdx.x * 256 + threadIdx.x) * 4;
  int c = (int)(b4 & (C_ - 1));
  int n = (int)(b4 >> 8);
  int g = n >> 9;
  float mu = st[g * 2], var = st[g * 2 + 1];
  float rs = rsqrtf(var + 1e-5f);
  uint2 v = *(const uint2*)(x2 + b4);
  float vv[4] = {u2f_lo(v.x), u2f_hi(v.x), u2f_lo(v.y), u2f_hi(v.y)};
  float oo[4];
  #pragma unroll
  for (int j = 0; j < 4; ++j) {
    int cc = c + j;
    float y = (vv[j] - mu) * rs * bf2f(lw[cc]) + bf2f(lb[cc]);
    oo[j] = gelu_f(y);
  }
  uint2 ov; ov.x = pack2(oo[0], oo[1]); ov.y = pack2(oo[2], oo[3]);
  *(uint2*)(x3 + b4) = ov;
}

// ---------------------------------------------------------------------------
// Pool: per-slice partials (grid 128x8) then combine.
__global__ __launch_bounds__(256) void pool_part(const ushort* __restrict__ x3,
    float* __restrict__ psum, float* __restrict__ pmax)
{
  const int g = blockIdx.x, sl = blockIdx.y, c = threadIdx.x;
  const ushort* p = x3 + ((size_t)g * NP_ + sl * 64) * C_ + c;
  float s = 0.0f, mx = -3.0e38f;
  #pragma unroll 4
  for (int r = 0; r < 64; ++r) {
    float v = bf2f(p[(size_t)r * C_]);
    s += v; mx = fmaxf(mx, v);
  }
  psum[((size_t)g * 8 + sl) * C_ + c] = s;
  pmax[((size_t)g * 8 + sl) * C_ + c] = mx;
}

__global__ __launch_bounds__(256) void pool_final(const float* __restrict__ psum,
    const float* __restrict__ pmax, float* __restrict__ pooled)
{
  const int g = blockIdx.x, c = threadIdx.x;
  float s = 0.0f, mx = -3.0e38f;
  #pragma unroll
  for (int sl = 0; sl < 8; ++sl) {
    s += psum[((size_t)g * 8 + sl) * C_ + c];
    mx = fmaxf(mx, pmax[((size_t)g * 8 + sl) * C_ + c]);
  }
  pooled[(size_t)g * C3_ + c]        = s * (1.0f / 512.0f);
  pooled[(size_t)g * C3_ + C_ + c]   = mx;
  pooled[(size_t)g * C3_ + 2*C_ + c] = s;
}

__global__ __launch_bounds__(256) void final_gemm(const float* __restrict__ pooled,
    const ushort* __restrict__ W, const ushort* __restrict__ b, void* __restrict__ out,
    const uint* __restrict__ flag)
{
  const int g = blockIdx.x, c = threadIdx.x;
  float acc = bf2f(b[c]);
  const float* p = pooled + (size_t)g * C3_;
  for (int k = 0; k < C3_; ++k) acc += p[k] * bf2f(W[(size_t)c * C3_ + k]);
  if (*flag) ((float*)out)[g * C_ + c] = acc;
  else       ((ushort*)out)[g * C_ + c] = f2bf(acc);
}

// ---------------------------------------------------------------------------
extern "C" void kernel_launch(void* const* d_in, const int* in_sizes, int n_in,
                              void* d_out, int out_size, void* d_ws, size_t ws_size,
                              hipStream_t stream)
{
  const int* ei   = (const int*)d_in[1];
  const int* srcp = ei;
  const int* dstp = ei + E_TOT;

  const size_t NC = (size_t)N_TOT * C_;                        // 16,777,216
  const size_t NEEDED = (4ull << 20) + 4 * NC * sizeof(ushort); // 132 MB
  if (ws_size < NEEDED) return;

  unsigned char* wsb = (unsigned char*)d_ws;
  uint*   deg    = (uint*)wsb;
  float*  m1     = (float*)(wsb + (256u << 10));
  float*  m2     = (float*)(wsb + (384u << 10));
  float*  lst    = (float*)(wsb + (512u << 10));
  uint*   flag   = (uint*)(wsb + (516u << 10));
  float*  pooled = (float*)(wsb + (520u << 10));
  ushort* PB     = (ushort*)(wsb + (1u << 20));       // param pool bf16
  ushort* S0     = (ushort*)(wsb + (4u << 20));       // x1
  ushort* S1     = S0 + NC;
  ushort* S2     = S1 + NC;
  ushort* S3     = S2 + NC;
  ushort* qkvb   = S1;                                // [N][768] overlay
  ushort* XB     = S3;                                // x bf16 (lower 16MB of S3)
  unsigned char* s3hi = (unsigned char*)(S3 + (size_t)N_TOT * DIN_);
  int*  csr    = (int*)s3hi;                          // 2 MB
  uint* rowptr = (uint*)(s3hi + (2u << 20));          // 256 KB
  uint* cursor = (uint*)(s3hi + (2u << 20) + (256u << 10));
  float* psum  = (float*)S2;                          // pool partials (S2 dead then)
  float* pmax  = psum + (size_t)B_GR * 8 * C_;

  // ---- dtype probe + import ----
  probe_dtype<<<1, 1, 0, stream>>>((const uint*)d_in[10], flag);
  CvtArgs ca;
  ca.s[0]  = { d_in[3],  O_L0LW };  ca.s[1]  = { d_in[4],  O_L0LB };
  ca.s[2]  = { d_in[5],  O_L0RW };  ca.s[3]  = { d_in[6],  O_L0RES };
  ca.s[4]  = { d_in[7],  O_LWL  };  ca.s[5]  = { d_in[8],  O_LBL  };
  ca.s[6]  = { d_in[9],  O_LWR  };  ca.s[7]  = { d_in[10], O_GNW  };
  ca.s[8]  = { d_in[11], O_GNB  };  ca.s[9]  = { d_in[12], O_GNA  };
  ca.s[10] = { d_in[13], O_AIW  };  ca.s[11] = { d_in[14], O_AIB  };
  ca.s[12] = { d_in[15], O_AOW  };  ca.s[13] = { d_in[16], O_AOB  };
  ca.s[14] = { d_in[17], O_LNW  };  ca.s[15] = { d_in[18], O_LNB  };
  ca.s[16] = { d_in[19], O_PLW  };  ca.s[17] = { d_in[20], O_PLB  };
  ca.s[18] = { nullptr,  TOTALP };
  cvt_params<<<(TOTALP + 255) / 256, 256, 0, stream>>>(ca, PB, flag);
  cvt_flat<<<(N_TOT * DIN_) / 256, 256, 0, stream>>>(d_in[0], XB, flag);

  // ---- degree + CSR build ----
  hipMemsetAsync(deg, 0, N_TOT * sizeof(uint), stream);
  hipMemsetAsync(wsb + (512u << 10), 0, 1024, stream);           // lst
  deg_count<<<E_TOT / 256, 256, 0, stream>>>(dstp, deg);
  scan_deg<<<B_GR, 512, 0, stream>>>(deg, rowptr, cursor);
  scatter_edges<<<E_TOT / 256, 256, 0, stream>>>(srcp, dstp, cursor, csr);

  // ---- layer 0 (DIN=128 -> C=256) ----
  sage_agg_csr<DIN_><<<N_TOT / 8, 256, 0, stream>>>(XB, csr, rowptr, deg, S1);
  hipMemsetAsync(wsb + (256u << 10), 0, 256u << 10, stream);     // m1+m2
  gemm_mfma<true, true><<<dim3(N_TOT / 64, 1), 256, 0, stream>>>(
      S1, DIN_, PB + O_L0LW, XB, DIN_, PB + O_L0RW, PB + O_L0LB, nullptr, S2, DIN_, C_, m1, m2);
  gemm_mfma<false, false><<<dim3(N_TOT / 64, 1), 256, 0, stream>>>(
      XB, DIN_, PB + O_L0RES, nullptr, 0, nullptr, nullptr, nullptr, S0, DIN_, C_, nullptr, nullptr);
  gn_gelu_add<<<(N_TOT * C_) / 1024, 256, 0, stream>>>(S2, S0, m1, m2,
      PB + O_GNW, PB + O_GNB, PB + O_GNA, S0);

  // ---- layers 1..3 (C -> C) ----
  for (int i = 0; i < 3; ++i) {
    sage_agg_csr<C_><<<N_TOT / 8, 256, 0, stream>>>(S0, csr, rowptr, deg, S1);
    hipMemsetAsync(wsb + (256u << 10), 0, 256u << 10, stream);   // m1+m2
    gemm_mfma<true, true><<<dim3(N_TOT / 64, 1), 256, 0, stream>>>(
        S1, C_, PB + O_LWL + (size_t)i * C_ * C_, S0, C_, PB + O_LWR + (size_t)i * C_ * C_,
        PB + O_LBL + i * C_, nullptr, S2, C_, C_, m1, m2);
    gn_gelu_add<<<(N_TOT * C_) / 1024, 256, 0, stream>>>(S2, S0, m1, m2,
        PB + O_GNW + (i + 1) * C_, PB + O_GNB + (i + 1) * C_, PB + O_GNA + (i + 1) * C_, S0);
  }

  // ---- attention ----
  gemm_mfma<false, false><<<dim3(N_TOT / 64, 3), 256, 0, stream>>>(
      S0, C_, PB + O_AIW, nullptr, 0, nullptr, PB + O_AIB, nullptr, qkvb, C_, C3_, nullptr, nullptr);
  attn_kernel<<<B_GR * H_, 1024, 0, stream>>>(qkvb);
  gemm_mfma<false, false><<<dim3(N_TOT / 64, 1), 256, 0, stream>>>(
      qkvb + C_, C3_, PB + O_AOW, nullptr, 0, nullptr, PB + O_AOB, S0, S0, C_, C_, nullptr, nullptr);

  // ---- graph LayerNorm + gelu ----
  ln_part<<<dim3(B_GR, 8), 256, 0, stream>>>(S0, lst);
  ln_finalize<<<1, B_GR, 0, stream>>>(lst);
  ln_gelu<<<(N_TOT * C_) / 1024, 256, 0, stream>>>(S0, lst, PB + O_LNW, PB + O_LNB, S1);

  // ---- pool + projection ----
  pool_part<<<dim3(B_GR, 8), 256, 0, stream>>>(S1, psum, pmax);
  pool_final<<<B_GR, 256, 0, stream>>>(psum, pmax, pooled);
  final_gemm<<<B_GR, 256, 0, stream>>>(pooled, PB + O_PLW, PB + O_PLB, d_out, flag);
}

// Round 11
// 1254.020 us; speedup vs baseline: 1.1702x; 1.1702x over previous
//
#include <hip/hip_runtime.h>

// ---------------------------------------------------------------------------
// GraphSAGE GNN forward, MI355X round 11:
//  - attention rebuilt flash-style: online softmax in 8-tile chunks (regs
//    ~80/wave, no spill), K read from global (LDS 150KB -> 77KB => 2 blk/CU,
//    16 waves/CU), o -> Q columns. R10's 1024-thr version spilled (VGPR 64,
//    790MB scratch writes).
//  - aggregation reverted to R9 wave-per-node (R10 half-wave was neutral).
// ---------------------------------------------------------------------------

#define N_TOT   65536
#define B_GR    128
#define NP_     512
#define E_TOT   524288
#define EPG     4096
#define DIN_    128
#define C_      256
#define C3_     768
#define H_      4

typedef unsigned int uint;
typedef unsigned short ushort;

// param pool element offsets (ushorts)
#define O_L0LW  0u
#define O_L0LB  32768u
#define O_L0RW  33024u
#define O_L0RES 65792u
#define O_LWL   98560u
#define O_LBL   295168u
#define O_LWR   295936u
#define O_GNW   492544u
#define O_GNB   493568u
#define O_GNA   494592u
#define O_AIW   495616u
#define O_AIB   692224u
#define O_AOW   692992u
#define O_AOB   758528u
#define O_LNW   758784u
#define O_LNB   759040u
#define O_PLW   759296u
#define O_PLB   955904u
#define TOTALP  956160u

typedef __attribute__((ext_vector_type(8))) short bf16x8_t;
typedef __attribute__((ext_vector_type(4))) float f32x4_t;

__device__ __forceinline__ float bf2f(ushort u){ union{uint i; float f;} v; v.i = ((uint)u) << 16; return v.f; }
__device__ __forceinline__ ushort f2bf(float f){
  union{float f; uint u;} v; v.f = f;
  uint u = v.u;
  u += 0x7fffu + ((u >> 16) & 1u);   // RNE
  return (ushort)(u >> 16);
}
__device__ __forceinline__ uint pack2(float a, float b){ return (uint)f2bf(a) | ((uint)f2bf(b) << 16); }
__device__ __forceinline__ float u2f_lo(uint u){ union{uint i; float f;} v; v.i = u << 16; return v.f; }
__device__ __forceinline__ float u2f_hi(uint u){ union{uint i; float f;} v; v.i = u & 0xffff0000u; return v.f; }
__device__ __forceinline__ float gelu_f(float x){ return 0.5f * x * (1.0f + erff(x * 0.70710678118654752440f)); }
__device__ __forceinline__ float wredsum(float v){
  #pragma unroll
  for (int off = 32; off; off >>= 1) v += __shfl_xor(v, off, 64);
  return v;
}

// ---------------------------------------------------------------------------
// dtype probe: gn_w[0]==1.0. f32 -> 0x3F800000 ; bf16 pair -> 0x3F803F80
__global__ void probe_dtype(const uint* __restrict__ gnw_raw, uint* __restrict__ flag){
  if (threadIdx.x == 0 && blockIdx.x == 0)
    *flag = (gnw_raw[0] == 0x3F800000u) ? 1u : 0u;   // 1 = f32 inputs
}

struct Seg { const void* p; uint ofs; };
struct CvtArgs { Seg s[19]; };

__global__ __launch_bounds__(256) void cvt_params(CvtArgs a, ushort* __restrict__ pb,
                                                  const uint* __restrict__ flag){
  uint gi = blockIdx.x * 256u + threadIdx.x;
  if (gi >= TOTALP) return;
  int lo = 0;
  #pragma unroll
  for (int s = 1; s < 18; ++s) if (gi >= a.s[s].ofs) lo = s;
  uint rel = gi - a.s[lo].ofs;
  pb[gi] = (*flag) ? f2bf(((const float*)a.s[lo].p)[rel]) : ((const ushort*)a.s[lo].p)[rel];
}

__global__ __launch_bounds__(256) void cvt_flat(const void* __restrict__ in, ushort* __restrict__ out,
                                                const uint* __restrict__ flag){
  uint i = blockIdx.x * 256u + threadIdx.x;
  out[i] = (*flag) ? f2bf(((const float*)in)[i]) : ((const ushort*)in)[i];
}

// ---------------------------------------------------------------------------
__global__ void deg_count(const int* __restrict__ dst, uint* __restrict__ deg){
  int e = blockIdx.x * 256 + threadIdx.x;
  atomicAdd(&deg[dst[e]], 1u);
}

// per-graph exclusive scan of deg (512 nodes) -> rowptr/cursor
__global__ __launch_bounds__(512) void scan_deg(const uint* __restrict__ deg,
    uint* __restrict__ rowptr, uint* __restrict__ cursor)
{
  __shared__ uint s[512];
  const int g = blockIdx.x, tid = threadIdx.x;
  uint v = deg[g * NP_ + tid];
  s[tid] = v;
  __syncthreads();
  #pragma unroll
  for (int off = 1; off < 512; off <<= 1) {
    uint t = (tid >= off) ? s[tid - off] : 0u;
    __syncthreads();
    s[tid] += t;
    __syncthreads();
  }
  uint p = g * EPG + (s[tid] - v);
  rowptr[g * NP_ + tid] = p;
  cursor[g * NP_ + tid] = p;
}

__global__ void scatter_edges(const int* __restrict__ src, const int* __restrict__ dst,
    uint* __restrict__ cursor, int* __restrict__ csr)
{
  int e = blockIdx.x * 256 + threadIdx.x;
  uint p = atomicAdd(&cursor[dst[e]], 1u);
  csr[p] = src[e];
}

// ---------------------------------------------------------------------------
// CSR mean-aggregation: one wave per node. Lane owns D/64 channels. (R9)
template<int D>
__global__ __launch_bounds__(256) void sage_agg_csr(const ushort* __restrict__ X,
    const int* __restrict__ csr, const uint* __restrict__ rowptr,
    const uint* __restrict__ deg, ushort* __restrict__ agg)
{
  constexpr int CPL = D / 64;
  const int tid = threadIdx.x, lane = tid & 63, wave = tid >> 6;
  const int n = blockIdx.x * 4 + wave;
  const uint start = rowptr[n];
  const uint dg = deg[n];
  const int co = lane * CPL;
  float acc[CPL];
  #pragma unroll
  for (int k = 0; k < CPL; ++k) acc[k] = 0.0f;

  auto addrow = [&](int s) {
    const ushort* r = X + (size_t)s * D + co;
    if constexpr (CPL == 2) {
      uint u = *(const uint*)r;
      acc[0] += u2f_lo(u); acc[1] += u2f_hi(u);
    } else {
      uint2 u = *(const uint2*)r;
      acc[0] += u2f_lo(u.x); acc[1] += u2f_hi(u.x);
      acc[2] += u2f_lo(u.y); acc[3] += u2f_hi(u.y);
    }
  };

  uint j = 0;
  for (; j + 4 <= dg; j += 4) {
    int s0 = csr[start + j],     s1 = csr[start + j + 1];
    int s2 = csr[start + j + 2], s3 = csr[start + j + 3];
    addrow(s0); addrow(s1); addrow(s2); addrow(s3);
  }
  for (; j < dg; ++j) addrow(csr[start + j]);

  float inv = 1.0f / (float)(dg < 1u ? 1u : dg);
  ushort* op = agg + (size_t)n * D + co;
  if constexpr (CPL == 2) {
    *(uint*)op = pack2(acc[0] * inv, acc[1] * inv);
  } else {
    uint2 o; o.x = pack2(acc[0] * inv, acc[1] * inv);
    o.y = pack2(acc[2] * inv, acc[3] * inv);
    *(uint2*)op = o;
  }
}

// ---------------------------------------------------------------------------
// MFMA GEMM v3: 64x256 block, 4 waves, wave = 64x64. A-stream prefetched.
// RN=true: fused SAGE row-L2-normalize + GraphNorm moment atomics.
template<bool DUAL, bool RN>
__global__ __launch_bounds__(256, 4) void gemm_mfma(
    const ushort* __restrict__ A1, int lda1, const ushort* __restrict__ W1,
    const ushort* __restrict__ A2, int lda2, const ushort* __restrict__ W2,
    const ushort* __restrict__ bias, const ushort* addend,   // addend may alias out
    ushort* out, int K, int ldOut,
    float* __restrict__ m1, float* __restrict__ m2)
{
  __shared__ float Cs[4][32 * 68];
  __shared__ float SSq[32];
  const int lane = threadIdx.x & 63, wave = threadIdx.x >> 6;
  const int lr = lane & 15, quad = lane >> 4;
  const int m0 = blockIdx.x * 64;
  const int n0 = blockIdx.y * 256 + wave * 64;
  f32x4_t acc[4][4];
  #pragma unroll
  for (int rt = 0; rt < 4; ++rt)
    #pragma unroll
    for (int ct = 0; ct < 4; ++ct) acc[rt][ct] = (f32x4_t){0.f, 0.f, 0.f, 0.f};
  {
    const ushort* ap = A1 + (size_t)(m0 + lr) * lda1 + quad * 8;
    const ushort* wp = W1 + (size_t)(n0 + lr) * K + quad * 8;
    bf16x8_t a[4];
    #pragma unroll
    for (int rt = 0; rt < 4; ++rt) a[rt] = *(const bf16x8_t*)(ap + (size_t)(rt * 16) * lda1);
    for (int kb = 0; kb < K; kb += 32) {
      int kn = (kb + 32 < K) ? kb + 32 : kb;
      bf16x8_t b[4], an[4];
      #pragma unroll
      for (int ct = 0; ct < 4; ++ct) b[ct] = *(const bf16x8_t*)(wp + (size_t)(ct * 16) * K + kb);
      #pragma unroll
      for (int rt = 0; rt < 4; ++rt) an[rt] = *(const bf16x8_t*)(ap + (size_t)(rt * 16) * lda1 + kn);
      #pragma unroll
      for (int rt = 0; rt < 4; ++rt)
        #pragma unroll
        for (int ct = 0; ct < 4; ++ct)
          acc[rt][ct] = __builtin_amdgcn_mfma_f32_16x16x32_bf16(a[rt], b[ct], acc[rt][ct], 0, 0, 0);
      #pragma unroll
      for (int rt = 0; rt < 4; ++rt) a[rt] = an[rt];
    }
  }
  if constexpr (DUAL) {
    const ushort* ap = A2 + (size_t)(m0 + lr) * lda2 + quad * 8;
    const ushort* wp = W2 + (size_t)(n0 + lr) * K + quad * 8;
    bf16x8_t a[4];
    #pragma unroll
    for (int rt = 0; rt < 4; ++rt) a[rt] = *(const bf16x8_t*)(ap + (size_t)(rt * 16) * lda2);
    for (int kb = 0; kb < K; kb += 32) {
      int kn = (kb + 32 < K) ? kb + 32 : kb;
      bf16x8_t b[4], an[4];
      #pragma unroll
      for (int ct = 0; ct < 4; ++ct) b[ct] = *(const bf16x8_t*)(wp + (size_t)(ct * 16) * K + kb);
      #pragma unroll
      for (int rt = 0; rt < 4; ++rt) an[rt] = *(const bf16x8_t*)(ap + (size_t)(rt * 16) * lda2 + kn);
      #pragma unroll
      for (int rt = 0; rt < 4; ++rt)
        #pragma unroll
        for (int ct = 0; ct < 4; ++ct)
          acc[rt][ct] = __builtin_amdgcn_mfma_f32_16x16x32_bf16(a[rt], b[ct], acc[rt][ct], 0, 0, 0);
      #pragma unroll
      for (int rt = 0; rt < 4; ++rt) a[rt] = an[rt];
    }
  }
  // ---- epilogue ----
  const int cb = lr * 4;
  float bv[4] = {0.f, 0.f, 0.f, 0.f};
  if (bias) {
    #pragma unroll
    for (int j = 0; j < 4; ++j) bv[j] = bf2f(bias[n0 + cb + j]);
  }
  float* cs = &Cs[wave][0];
  float a1s[4] = {0.f, 0.f, 0.f, 0.f}, a2s[4] = {0.f, 0.f, 0.f, 0.f};
  #pragma unroll
  for (int round = 0; round < 2; ++round) {
    #pragma unroll
    for (int rt2 = 0; rt2 < 2; ++rt2) {
      int rt = round * 2 + rt2;
      #pragma unroll
      for (int ct = 0; ct < 4; ++ct)
        #pragma unroll
        for (int r = 0; r < 4; ++r) {
          float v = acc[rt][ct][r];
          if constexpr (RN) v += bias ? bf2f(bias[n0 + ct * 16 + lr]) : 0.0f;
          cs[(rt2 * 16 + quad * 4 + r) * 68 + ct * 16 + lr] = v;
        }
    }
    if constexpr (RN) { if (threadIdx.x < 32) SSq[threadIdx.x] = 0.0f; }
    __syncthreads();
    if constexpr (RN) {
      #pragma unroll
      for (int it = 0; it < 8; ++it) {
        int Lr = it * 4 + quad;
        float4 v = *(const float4*)(cs + Lr * 68 + cb);
        float ss = v.x*v.x + v.y*v.y + v.z*v.z + v.w*v.w;
        #pragma unroll
        for (int off = 1; off < 16; off <<= 1) ss += __shfl_xor(ss, off, 64);
        if (lr == 0) atomicAdd(&SSq[Lr], ss);
      }
      __syncthreads();
      #pragma unroll
      for (int it = 0; it < 8; ++it) {
        int Lr = it * 4 + quad;
        float inv = 1.0f / fmaxf(sqrtf(SSq[Lr]), 1e-12f);
        float4 v = *(const float4*)(cs + Lr * 68 + cb);
        float r0 = v.x * inv, r1 = v.y * inv, r2 = v.z * inv, r3 = v.w * inv;
        a1s[0] += r0; a1s[1] += r1; a1s[2] += r2; a1s[3] += r3;
        a2s[0] += r0*r0; a2s[1] += r1*r1; a2s[2] += r2*r2; a2s[3] += r3*r3;
        size_t ob = (size_t)(m0 + round * 32 + Lr) * ldOut + n0 + cb;
        uint2 o; o.x = pack2(r0, r1); o.y = pack2(r2, r3);
        *(uint2*)(out + ob) = o;
      }
    } else {
      #pragma unroll
      for (int it = 0; it < 8; ++it) {
        int Lr = it * 4 + quad;
        float4 v = *(const float4*)(cs + Lr * 68 + cb);
        int grow = m0 + round * 32 + Lr;
        size_t ob = (size_t)grow * ldOut + n0 + cb;
        float r0 = v.x + bv[0], r1 = v.y + bv[1], r2 = v.z + bv[2], r3 = v.w + bv[3];
        if (addend) {
          uint2 ad = *(const uint2*)(addend + ob);
          r0 += u2f_lo(ad.x); r1 += u2f_hi(ad.x);
          r2 += u2f_lo(ad.y); r3 += u2f_hi(ad.y);
        }
        uint2 o; o.x = pack2(r0, r1); o.y = pack2(r2, r3);
        *(uint2*)(out + ob) = o;
      }
    }
    __syncthreads();
  }
  if constexpr (RN) {
    const int g = m0 >> 9;
    #pragma unroll
    for (int k = 0; k < 4; ++k) {
      atomicAdd(&m1[g*C_ + n0 + cb + k], a1s[k]);
      atomicAdd(&m2[g*C_ + n0 + cb + k], a2s[k]);
    }
  }
}

// GraphNorm + GELU + residual. m1/m2 hold SUMS over 512 nodes.
__global__ __launch_bounds__(256) void gn_gelu_add(const ushort* __restrict__ h,
    const ushort* res,
    const float* __restrict__ m1, const float* __restrict__ m2,
    const ushort* __restrict__ gw, const ushort* __restrict__ gb, const ushort* __restrict__ ga,
    ushort* out)
{
  size_t b4 = ((size_t)blockIdx.x * 256 + threadIdx.x) * 4;
  int c = (int)(b4 & (C_ - 1));
  int n = (int)(b4 >> 8);
  int g = n >> 9;
  uint2 hv = *(const uint2*)(h + b4);
  uint2 rv = *(const uint2*)(res + b4);
  float hh[4] = {u2f_lo(hv.x), u2f_hi(hv.x), u2f_lo(hv.y), u2f_hi(hv.y)};
  float rr[4] = {u2f_lo(rv.x), u2f_hi(rv.x), u2f_lo(rv.y), u2f_hi(rv.y)};
  float oo[4];
  #pragma unroll
  for (int j = 0; j < 4; ++j) {
    int cc = c + j;
    float a  = bf2f(ga[cc]);
    float mm = m1[g*C_ + cc] * (1.0f / 512.0f);
    float q2 = m2[g*C_ + cc] * (1.0f / 512.0f);
    float var = q2 - a * (2.0f - a) * mm * mm;
    float xo = hh[j] - a * mm;
    float y = bf2f(gw[cc]) * xo * rsqrtf(var + 1e-5f) + bf2f(gb[cc]);
    oo[j] = gelu_f(y) + rr[j];
  }
  uint2 ov; ov.x = pack2(oo[0], oo[1]); ov.y = pack2(oo[2], oo[3]);
  *(uint2*)(out + b4) = ov;
}

// ---------------------------------------------------------------------------
// Flash-style MFMA attention: one block (512 thr = 8 waves) per (graph,head).
// LDS = Vt 66,560 + Pw 10,240 = 76,800 B -> 2 blocks/CU (16 waves/CU).
// K is read directly from global (stays live); online softmax over 4 chunks
// of 8 tiles keeps regs ~80/wave. Output o -> Q columns (dead per-wave after
// the wave reads its own Q rows); out-proj reads qkv col 0.
#define VT_P 520
#define PW_P 40
__global__ __launch_bounds__(512, 2) void attn_kernel(ushort* __restrict__ qkv)
{
  __shared__ ushort Vt[64 * VT_P];        // V^T[c][j]
  __shared__ ushort Pw[8][16 * PW_P];     // per-wave P chunk (16x32)
  const int bid = blockIdx.x;
  const int g = bid >> 2, h = bid & 3;
  const int tid = threadIdx.x, lane = tid & 63, wave = tid >> 6;
  const int lr = lane & 15, quad = lane >> 4;
  const size_t base = (size_t)g * NP_ * C3_;
  const int qoff = h * 64, koff = C_ + h * 64, voff = 2 * C_ + h * 64;
  for (int idx = tid; idx < NP_ * 64; idx += 512) {
    int j = idx >> 6, c = idx & 63;
    Vt[c * VT_P + j] = qkv[base + (size_t)j * C3_ + voff + c];
  }
  __syncthreads();
  ushort* pw = &Pw[wave][0];
  const ushort* kbase = qkv + base + koff + quad * 8;
  const int q0 = wave * 64;
  for (int qt = 0; qt < 4; ++qt) {
    const int qr = q0 + qt * 16;
    const ushort* qp = qkv + base + (size_t)(qr + lr) * C3_ + qoff + quad * 8;
    bf16x8_t qa0 = *(const bf16x8_t*)(qp);
    bf16x8_t qa1 = *(const bf16x8_t*)(qp + 32);
    float mrow[4] = {-1e30f, -1e30f, -1e30f, -1e30f};
    float psum[4] = {0.f, 0.f, 0.f, 0.f};
    f32x4_t o[4];
    #pragma unroll
    for (int nt = 0; nt < 4; ++nt) o[nt] = (f32x4_t){0.f, 0.f, 0.f, 0.f};
    for (int ch = 0; ch < 4; ++ch) {
      f32x4_t s[8];
      #pragma unroll
      for (int t8 = 0; t8 < 8; ++t8) {
        int t = ch * 8 + t8;
        const ushort* kp = kbase + (size_t)(t * 16 + lr) * C3_;
        bf16x8_t b0 = *(const bf16x8_t*)(kp);
        bf16x8_t b1 = *(const bf16x8_t*)(kp + 32);
        f32x4_t a = (f32x4_t){0.f, 0.f, 0.f, 0.f};
        a = __builtin_amdgcn_mfma_f32_16x16x32_bf16(qa0, b0, a, 0, 0, 0);
        a = __builtin_amdgcn_mfma_f32_16x16x32_bf16(qa1, b1, a, 0, 0, 0);
        s[t8] = a;
      }
      #pragma unroll
      for (int r = 0; r < 4; ++r) {
        float cm = s[0][r];
        #pragma unroll
        for (int t8 = 1; t8 < 8; ++t8) cm = fmaxf(cm, s[t8][r]);
        #pragma unroll
        for (int off = 8; off; off >>= 1) cm = fmaxf(cm, __shfl_xor(cm, off, 64));
        float mn = fmaxf(mrow[r], cm);
        float alpha = __expf((mrow[r] - mn) * 0.125f);
        mrow[r] = mn;
        float cs = 0.0f;
        #pragma unroll
        for (int t8 = 0; t8 < 8; ++t8) {
          float e = __expf((s[t8][r] - mn) * 0.125f);
          s[t8][r] = e; cs += e;
        }
        psum[r] = psum[r] * alpha + cs;
        #pragma unroll
        for (int nt = 0; nt < 4; ++nt) o[nt][r] *= alpha;
      }
      // PV over this chunk (p unnormalized; divide by sum at the end)
      #pragma unroll
      for (int kc2 = 0; kc2 < 4; ++kc2) {
        #pragma unroll
        for (int half = 0; half < 2; ++half) {
          int t8 = kc2 * 2 + half;
          #pragma unroll
          for (int r = 0; r < 4; ++r)
            pw[(quad * 4 + r) * PW_P + half * 16 + lr] = f2bf(s[t8][r]);
        }
        __threadfence_block();
        bf16x8_t pa = *(const bf16x8_t*)(pw + lr * PW_P + quad * 8);
        const int kg = ch * 128 + kc2 * 32;
        #pragma unroll
        for (int nt = 0; nt < 4; ++nt) {
          const ushort* vp = Vt + (size_t)(nt * 16 + lr) * VT_P + kg + quad * 8;
          bf16x8_t b = *(const bf16x8_t*)(vp);
          o[nt] = __builtin_amdgcn_mfma_f32_16x16x32_bf16(pa, b, o[nt], 0, 0, 0);
        }
      }
    }
    // finalize: reduce row sums across the 16-lane group, normalize, store
    #pragma unroll
    for (int r = 0; r < 4; ++r) {
      float sm = psum[r];
      #pragma unroll
      for (int off = 8; off; off >>= 1) sm += __shfl_xor(sm, off, 64);
      float inv = 1.0f / sm;
      #pragma unroll
      for (int nt = 0; nt < 4; ++nt) o[nt][r] *= inv;
    }
    #pragma unroll
    for (int nt = 0; nt < 4; ++nt)
      #pragma unroll
      for (int r = 0; r < 4; ++r)
        qkv[base + (size_t)(qr + quad * 4 + r) * C3_ + qoff + nt * 16 + lr] =
            f2bf(o[nt][r]);
  }
}

// ---------------------------------------------------------------------------
// Graph-LN: partial sums (grid 128x8) -> atomics; finalize converts to mu/var.
__global__ __launch_bounds__(256) void ln_part(const ushort* __restrict__ x2, float* __restrict__ st)
{
  __shared__ float a1[4], a2[4];
  const int g = blockIdx.x, sl = blockIdx.y;
  const int tid = threadIdx.x, lane = tid & 63, wave = tid >> 6;
  const ushort* p = x2 + ((size_t)g * NP_ + sl * 64) * C_;
  float s = 0.0f, q = 0.0f;
  for (int i = tid; i < 64 * C_; i += 256) { float v = bf2f(p[i]); s += v; q += v * v; }
  s = wredsum(s); q = wredsum(q);
  if (lane == 0) { a1[wave] = s; a2[wave] = q; }
  __syncthreads();
  if (tid == 0) {
    atomicAdd(&st[g * 2],     a1[0] + a1[1] + a1[2] + a1[3]);
    atomicAdd(&st[g * 2 + 1], a2[0] + a2[1] + a2[2] + a2[3]);
  }
}

__global__ void ln_finalize(float* __restrict__ st)
{
  int g = threadIdx.x;
  float S = st[g * 2], Q = st[g * 2 + 1];
  float mu = S * (1.0f / (NP_ * C_));
  float var = Q * (1.0f / (NP_ * C_)) - mu * mu;
  st[g * 2] = mu; st[g * 2 + 1] = var;
}

__global__ __launch_bounds__(256) void ln_gelu(const ushort* __restrict__ x2, const float* __restrict__ st,
    const ushort* __restrict__ lw, const ushort* __restrict__ lb, ushort* __restrict__ x3)
{
  size_t b4 = ((size_t)blockIdx.x * 256 + threadIdx.x) * 4;
  int c = (int)(b4 & (C_ - 1));
  int n = (int)(b4 >> 8);
  int g = n >> 9;
  float mu = st[g * 2], var = st[g * 2 + 1];
  float rs = rsqrtf(var + 1e-5f);
  uint2 v = *(const uint2*)(x2 + b4);
  float vv[4] = {u2f_lo(v.x), u2f_hi(v.x), u2f_lo(v.y), u2f_hi(v.y)};
  float oo[4];
  #pragma unroll
  for (int j = 0; j < 4; ++j) {
    int cc = c + j;
    float y = (vv[j] - mu) * rs * bf2f(lw[cc]) + bf2f(lb[cc]);
    oo[j] = gelu_f(y);
  }
  uint2 ov; ov.x = pack2(oo[0], oo[1]); ov.y = pack2(oo[2], oo[3]);
  *(uint2*)(x3 + b4) = ov;
}

// ---------------------------------------------------------------------------
// Pool: per-slice partials (grid 128x8) then combine.
__global__ __launch_bounds__(256) void pool_part(const ushort* __restrict__ x3,
    float* __restrict__ psum, float* __restrict__ pmax)
{
  const int g = blockIdx.x, sl = blockIdx.y, c = threadIdx.x;
  const ushort* p = x3 + ((size_t)g * NP_ + sl * 64) * C_ + c;
  float s = 0.0f, mx = -3.0e38f;
  #pragma unroll 4
  for (int r = 0; r < 64; ++r) {
    float v = bf2f(p[(size_t)r * C_]);
    s += v; mx = fmaxf(mx, v);
  }
  psum[((size_t)g * 8 + sl) * C_ + c] = s;
  pmax[((size_t)g * 8 + sl) * C_ + c] = mx;
}

__global__ __launch_bounds__(256) void pool_final(const float* __restrict__ psum,
    const float* __restrict__ pmax, float* __restrict__ pooled)
{
  const int g = blockIdx.x, c = threadIdx.x;
  float s = 0.0f, mx = -3.0e38f;
  #pragma unroll
  for (int sl = 0; sl < 8; ++sl) {
    s += psum[((size_t)g * 8 + sl) * C_ + c];
    mx = fmaxf(mx, pmax[((size_t)g * 8 + sl) * C_ + c]);
  }
  pooled[(size_t)g * C3_ + c]        = s * (1.0f / 512.0f);
  pooled[(size_t)g * C3_ + C_ + c]   = mx;
  pooled[(size_t)g * C3_ + 2*C_ + c] = s;
}

__global__ __launch_bounds__(256) void final_gemm(const float* __restrict__ pooled,
    const ushort* __restrict__ W, const ushort* __restrict__ b, void* __restrict__ out,
    const uint* __restrict__ flag)
{
  const int g = blockIdx.x, c = threadIdx.x;
  float acc = bf2f(b[c]);
  const float* p = pooled + (size_t)g * C3_;
  for (int k = 0; k < C3_; ++k) acc += p[k] * bf2f(W[(size_t)c * C3_ + k]);
  if (*flag) ((float*)out)[g * C_ + c] = acc;
  else       ((ushort*)out)[g * C_ + c] = f2bf(acc);
}

// ---------------------------------------------------------------------------
extern "C" void kernel_launch(void* const* d_in, const int* in_sizes, int n_in,
                              void* d_out, int out_size, void* d_ws, size_t ws_size,
                              hipStream_t stream)
{
  const int* ei   = (const int*)d_in[1];
  const int* srcp = ei;
  const int* dstp = ei + E_TOT;

  const size_t NC = (size_t)N_TOT * C_;                        // 16,777,216
  const size_t NEEDED = (4ull << 20) + 4 * NC * sizeof(ushort); // 132 MB
  if (ws_size < NEEDED) return;

  unsigned char* wsb = (unsigned char*)d_ws;
  uint*   deg    = (uint*)wsb;
  float*  m1     = (float*)(wsb + (256u << 10));
  float*  m2     = (float*)(wsb + (384u << 10));
  float*  lst    = (float*)(wsb + (512u << 10));
  uint*   flag   = (uint*)(wsb + (516u << 10));
  float*  pooled = (float*)(wsb + (520u << 10));
  ushort* PB     = (ushort*)(wsb + (1u << 20));       // param pool bf16
  ushort* S0     = (ushort*)(wsb + (4u << 20));       // x1
  ushort* S1     = S0 + NC;
  ushort* S2     = S1 + NC;
  ushort* S3     = S2 + NC;
  ushort* qkvb   = S1;                                // [N][768] overlay
  ushort* XB     = S3;                                // x bf16 (lower 16MB of S3)
  unsigned char* s3hi = (unsigned char*)(S3 + (size_t)N_TOT * DIN_);
  int*  csr    = (int*)s3hi;                          // 2 MB
  uint* rowptr = (uint*)(s3hi + (2u << 20));          // 256 KB
  uint* cursor = (uint*)(s3hi + (2u << 20) + (256u << 10));
  float* psum  = (float*)S2;                          // pool partials (S2 dead then)
  float* pmax  = psum + (size_t)B_GR * 8 * C_;

  // ---- dtype probe + import ----
  probe_dtype<<<1, 1, 0, stream>>>((const uint*)d_in[10], flag);
  CvtArgs ca;
  ca.s[0]  = { d_in[3],  O_L0LW };  ca.s[1]  = { d_in[4],  O_L0LB };
  ca.s[2]  = { d_in[5],  O_L0RW };  ca.s[3]  = { d_in[6],  O_L0RES };
  ca.s[4]  = { d_in[7],  O_LWL  };  ca.s[5]  = { d_in[8],  O_LBL  };
  ca.s[6]  = { d_in[9],  O_LWR  };  ca.s[7]  = { d_in[10], O_GNW  };
  ca.s[8]  = { d_in[11], O_GNB  };  ca.s[9]  = { d_in[12], O_GNA  };
  ca.s[10] = { d_in[13], O_AIW  };  ca.s[11] = { d_in[14], O_AIB  };
  ca.s[12] = { d_in[15], O_AOW  };  ca.s[13] = { d_in[16], O_AOB  };
  ca.s[14] = { d_in[17], O_LNW  };  ca.s[15] = { d_in[18], O_LNB  };
  ca.s[16] = { d_in[19], O_PLW  };  ca.s[17] = { d_in[20], O_PLB  };
  ca.s[18] = { nullptr,  TOTALP };
  cvt_params<<<(TOTALP + 255) / 256, 256, 0, stream>>>(ca, PB, flag);
  cvt_flat<<<(N_TOT * DIN_) / 256, 256, 0, stream>>>(d_in[0], XB, flag);

  // ---- degree + CSR build ----
  hipMemsetAsync(deg, 0, N_TOT * sizeof(uint), stream);
  hipMemsetAsync(wsb + (512u << 10), 0, 1024, stream);           // lst
  deg_count<<<E_TOT / 256, 256, 0, stream>>>(dstp, deg);
  scan_deg<<<B_GR, 512, 0, stream>>>(deg, rowptr, cursor);
  scatter_edges<<<E_TOT / 256, 256, 0, stream>>>(srcp, dstp, cursor, csr);

  // ---- layer 0 (DIN=128 -> C=256) ----
  sage_agg_csr<DIN_><<<N_TOT / 4, 256, 0, stream>>>(XB, csr, rowptr, deg, S1);
  hipMemsetAsync(wsb + (256u << 10), 0, 256u << 10, stream);     // m1+m2
  gemm_mfma<true, true><<<dim3(N_TOT / 64, 1), 256, 0, stream>>>(
      S1, DIN_, PB + O_L0LW, XB, DIN_, PB + O_L0RW, PB + O_L0LB, nullptr, S2, DIN_, C_, m1, m2);
  gemm_mfma<false, false><<<dim3(N_TOT / 64, 1), 256, 0, stream>>>(
      XB, DIN_, PB + O_L0RES, nullptr, 0, nullptr, nullptr, nullptr, S0, DIN_, C_, nullptr, nullptr);
  gn_gelu_add<<<(N_TOT * C_) / 1024, 256, 0, stream>>>(S2, S0, m1, m2,
      PB + O_GNW, PB + O_GNB, PB + O_GNA, S0);

  // ---- layers 1..3 (C -> C) ----
  for (int i = 0; i < 3; ++i) {
    sage_agg_csr<C_><<<N_TOT / 4, 256, 0, stream>>>(S0, csr, rowptr, deg, S1);
    hipMemsetAsync(wsb + (256u << 10), 0, 256u << 10, stream);   // m1+m2
    gemm_mfma<true, true><<<dim3(N_TOT / 64, 1), 256, 0, stream>>>(
        S1, C_, PB + O_LWL + (size_t)i * C_ * C_, S0, C_, PB + O_LWR + (size_t)i * C_ * C_,
        PB + O_LBL + i * C_, nullptr, S2, C_, C_, m1, m2);
    gn_gelu_add<<<(N_TOT * C_) / 1024, 256, 0, stream>>>(S2, S0, m1, m2,
        PB + O_GNW + (i + 1) * C_, PB + O_GNB + (i + 1) * C_, PB + O_GNA + (i + 1) * C_, S0);
  }

  // ---- attention ----
  gemm_mfma<false, false><<<dim3(N_TOT / 64, 3), 256, 0, stream>>>(
      S0, C_, PB + O_AIW, nullptr, 0, nullptr, PB + O_AIB, nullptr, qkvb, C_, C3_, nullptr, nullptr);
  attn_kernel<<<B_GR * H_, 512, 0, stream>>>(qkvb);
  // o lives in the Q columns now (ld 768)
  gemm_mfma<false, false><<<dim3(N_TOT / 64, 1), 256, 0, stream>>>(
      qkvb, C3_, PB + O_AOW, nullptr, 0, nullptr, PB + O_AOB, S0, S0, C_, C_, nullptr, nullptr);

  // ---- graph LayerNorm + gelu ----
  ln_part<<<dim3(B_GR, 8), 256, 0, stream>>>(S0, lst);
  ln_finalize<<<1, B_GR, 0, stream>>>(lst);
  ln_gelu<<<(N_TOT * C_) / 1024, 256, 0, stream>>>(S0, lst, PB + O_LNW, PB + O_LNB, S1);

  // ---- pool + projection ----
  pool_part<<<dim3(B_GR, 8), 256, 0, stream>>>(S1, psum, pmax);
  pool_final<<<B_GR, 256, 0, stream>>>(psum, pmax, pooled);
  final_gemm<<<B_GR, 256, 0, stream>>>(pooled, PB + O_PLW, PB + O_PLB, d_out, flag);
}

// Round 12
// 1184.266 us; speedup vs baseline: 1.2392x; 1.0589x over previous
//
#include <hip/hip_runtime.h>

// ---------------------------------------------------------------------------
// GraphSAGE GNN forward, MI355X round 12: R9 config (best: 1207us) +
//  - attention reverted to R9 LDS-resident version (112us; R10 spilled,
//    R11 flash re-read K 4x -> both slower)
//  - per-layer m1/m2 buffers, single upfront memset
//  - ln partials without atomics; ln_finalize folded into ln_gelu
//  - pool_final folded into final_gemm
// ---------------------------------------------------------------------------

#define N_TOT   65536
#define B_GR    128
#define NP_     512
#define E_TOT   524288
#define EPG     4096
#define DIN_    128
#define C_      256
#define C3_     768
#define H_      4

typedef unsigned int uint;
typedef unsigned short ushort;

// param pool element offsets (ushorts)
#define O_L0LW  0u
#define O_L0LB  32768u
#define O_L0RW  33024u
#define O_L0RES 65792u
#define O_LWL   98560u
#define O_LBL   295168u
#define O_LWR   295936u
#define O_GNW   492544u
#define O_GNB   493568u
#define O_GNA   494592u
#define O_AIW   495616u
#define O_AIB   692224u
#define O_AOW   692992u
#define O_AOB   758528u
#define O_LNW   758784u
#define O_LNB   759040u
#define O_PLW   759296u
#define O_PLB   955904u
#define TOTALP  956160u

typedef __attribute__((ext_vector_type(8))) short bf16x8_t;
typedef __attribute__((ext_vector_type(4))) float f32x4_t;

__device__ __forceinline__ float bf2f(ushort u){ union{uint i; float f;} v; v.i = ((uint)u) << 16; return v.f; }
__device__ __forceinline__ ushort f2bf(float f){
  union{float f; uint u;} v; v.f = f;
  uint u = v.u;
  u += 0x7fffu + ((u >> 16) & 1u);   // RNE
  return (ushort)(u >> 16);
}
__device__ __forceinline__ uint pack2(float a, float b){ return (uint)f2bf(a) | ((uint)f2bf(b) << 16); }
__device__ __forceinline__ float u2f_lo(uint u){ union{uint i; float f;} v; v.i = u << 16; return v.f; }
__device__ __forceinline__ float u2f_hi(uint u){ union{uint i; float f;} v; v.i = u & 0xffff0000u; return v.f; }
__device__ __forceinline__ float gelu_f(float x){ return 0.5f * x * (1.0f + erff(x * 0.70710678118654752440f)); }
__device__ __forceinline__ float wredsum(float v){
  #pragma unroll
  for (int off = 32; off; off >>= 1) v += __shfl_xor(v, off, 64);
  return v;
}

// ---------------------------------------------------------------------------
// dtype probe: gn_w[0]==1.0. f32 -> 0x3F800000 ; bf16 pair -> 0x3F803F80
__global__ void probe_dtype(const uint* __restrict__ gnw_raw, uint* __restrict__ flag){
  if (threadIdx.x == 0 && blockIdx.x == 0)
    *flag = (gnw_raw[0] == 0x3F800000u) ? 1u : 0u;   // 1 = f32 inputs
}

struct Seg { const void* p; uint ofs; };
struct CvtArgs { Seg s[19]; };

__global__ __launch_bounds__(256) void cvt_params(CvtArgs a, ushort* __restrict__ pb,
                                                  const uint* __restrict__ flag){
  uint gi = blockIdx.x * 256u + threadIdx.x;
  if (gi >= TOTALP) return;
  int lo = 0;
  #pragma unroll
  for (int s = 1; s < 18; ++s) if (gi >= a.s[s].ofs) lo = s;
  uint rel = gi - a.s[lo].ofs;
  pb[gi] = (*flag) ? f2bf(((const float*)a.s[lo].p)[rel]) : ((const ushort*)a.s[lo].p)[rel];
}

__global__ __launch_bounds__(256) void cvt_flat(const void* __restrict__ in, ushort* __restrict__ out,
                                                const uint* __restrict__ flag){
  uint i = blockIdx.x * 256u + threadIdx.x;
  out[i] = (*flag) ? f2bf(((const float*)in)[i]) : ((const ushort*)in)[i];
}

// ---------------------------------------------------------------------------
__global__ void deg_count(const int* __restrict__ dst, uint* __restrict__ deg){
  int e = blockIdx.x * 256 + threadIdx.x;
  atomicAdd(&deg[dst[e]], 1u);
}

// per-graph exclusive scan of deg (512 nodes) -> rowptr/cursor
__global__ __launch_bounds__(512) void scan_deg(const uint* __restrict__ deg,
    uint* __restrict__ rowptr, uint* __restrict__ cursor)
{
  __shared__ uint s[512];
  const int g = blockIdx.x, tid = threadIdx.x;
  uint v = deg[g * NP_ + tid];
  s[tid] = v;
  __syncthreads();
  #pragma unroll
  for (int off = 1; off < 512; off <<= 1) {
    uint t = (tid >= off) ? s[tid - off] : 0u;
    __syncthreads();
    s[tid] += t;
    __syncthreads();
  }
  uint p = g * EPG + (s[tid] - v);
  rowptr[g * NP_ + tid] = p;
  cursor[g * NP_ + tid] = p;
}

__global__ void scatter_edges(const int* __restrict__ src, const int* __restrict__ dst,
    uint* __restrict__ cursor, int* __restrict__ csr)
{
  int e = blockIdx.x * 256 + threadIdx.x;
  uint p = atomicAdd(&cursor[dst[e]], 1u);
  csr[p] = src[e];
}

// ---------------------------------------------------------------------------
// CSR mean-aggregation: one wave per node. Lane owns D/64 channels.
template<int D>
__global__ __launch_bounds__(256) void sage_agg_csr(const ushort* __restrict__ X,
    const int* __restrict__ csr, const uint* __restrict__ rowptr,
    const uint* __restrict__ deg, ushort* __restrict__ agg)
{
  constexpr int CPL = D / 64;
  const int tid = threadIdx.x, lane = tid & 63, wave = tid >> 6;
  const int n = blockIdx.x * 4 + wave;
  const uint start = rowptr[n];
  const uint dg = deg[n];
  const int co = lane * CPL;
  float acc[CPL];
  #pragma unroll
  for (int k = 0; k < CPL; ++k) acc[k] = 0.0f;

  auto addrow = [&](int s) {
    const ushort* r = X + (size_t)s * D + co;
    if constexpr (CPL == 2) {
      uint u = *(const uint*)r;
      acc[0] += u2f_lo(u); acc[1] += u2f_hi(u);
    } else {
      uint2 u = *(const uint2*)r;
      acc[0] += u2f_lo(u.x); acc[1] += u2f_hi(u.x);
      acc[2] += u2f_lo(u.y); acc[3] += u2f_hi(u.y);
    }
  };

  uint j = 0;
  for (; j + 4 <= dg; j += 4) {
    int s0 = csr[start + j],     s1 = csr[start + j + 1];
    int s2 = csr[start + j + 2], s3 = csr[start + j + 3];
    addrow(s0); addrow(s1); addrow(s2); addrow(s3);
  }
  for (; j < dg; ++j) addrow(csr[start + j]);

  float inv = 1.0f / (float)(dg < 1u ? 1u : dg);
  ushort* op = agg + (size_t)n * D + co;
  if constexpr (CPL == 2) {
    *(uint*)op = pack2(acc[0] * inv, acc[1] * inv);
  } else {
    uint2 o; o.x = pack2(acc[0] * inv, acc[1] * inv);
    o.y = pack2(acc[2] * inv, acc[3] * inv);
    *(uint2*)op = o;
  }
}

// ---------------------------------------------------------------------------
// MFMA GEMM v3: 64x256 block, 4 waves, wave = 64x64. A-stream prefetched.
// RN=true: fused SAGE row-L2-normalize + GraphNorm moment atomics.
template<bool DUAL, bool RN>
__global__ __launch_bounds__(256, 4) void gemm_mfma(
    const ushort* __restrict__ A1, int lda1, const ushort* __restrict__ W1,
    const ushort* __restrict__ A2, int lda2, const ushort* __restrict__ W2,
    const ushort* __restrict__ bias, const ushort* addend,   // addend may alias out
    ushort* out, int K, int ldOut,
    float* __restrict__ m1, float* __restrict__ m2)
{
  __shared__ float Cs[4][32 * 68];
  __shared__ float SSq[32];
  const int lane = threadIdx.x & 63, wave = threadIdx.x >> 6;
  const int lr = lane & 15, quad = lane >> 4;
  const int m0 = blockIdx.x * 64;
  const int n0 = blockIdx.y * 256 + wave * 64;
  f32x4_t acc[4][4];
  #pragma unroll
  for (int rt = 0; rt < 4; ++rt)
    #pragma unroll
    for (int ct = 0; ct < 4; ++ct) acc[rt][ct] = (f32x4_t){0.f, 0.f, 0.f, 0.f};
  {
    const ushort* ap = A1 + (size_t)(m0 + lr) * lda1 + quad * 8;
    const ushort* wp = W1 + (size_t)(n0 + lr) * K + quad * 8;
    bf16x8_t a[4];
    #pragma unroll
    for (int rt = 0; rt < 4; ++rt) a[rt] = *(const bf16x8_t*)(ap + (size_t)(rt * 16) * lda1);
    for (int kb = 0; kb < K; kb += 32) {
      int kn = (kb + 32 < K) ? kb + 32 : kb;
      bf16x8_t b[4], an[4];
      #pragma unroll
      for (int ct = 0; ct < 4; ++ct) b[ct] = *(const bf16x8_t*)(wp + (size_t)(ct * 16) * K + kb);
      #pragma unroll
      for (int rt = 0; rt < 4; ++rt) an[rt] = *(const bf16x8_t*)(ap + (size_t)(rt * 16) * lda1 + kn);
      #pragma unroll
      for (int rt = 0; rt < 4; ++rt)
        #pragma unroll
        for (int ct = 0; ct < 4; ++ct)
          acc[rt][ct] = __builtin_amdgcn_mfma_f32_16x16x32_bf16(a[rt], b[ct], acc[rt][ct], 0, 0, 0);
      #pragma unroll
      for (int rt = 0; rt < 4; ++rt) a[rt] = an[rt];
    }
  }
  if constexpr (DUAL) {
    const ushort* ap = A2 + (size_t)(m0 + lr) * lda2 + quad * 8;
    const ushort* wp = W2 + (size_t)(n0 + lr) * K + quad * 8;
    bf16x8_t a[4];
    #pragma unroll
    for (int rt = 0; rt < 4; ++rt) a[rt] = *(const bf16x8_t*)(ap + (size_t)(rt * 16) * lda2);
    for (int kb = 0; kb < K; kb += 32) {
      int kn = (kb + 32 < K) ? kb + 32 : kb;
      bf16x8_t b[4], an[4];
      #pragma unroll
      for (int ct = 0; ct < 4; ++ct) b[ct] = *(const bf16x8_t*)(wp + (size_t)(ct * 16) * K + kb);
      #pragma unroll
      for (int rt = 0; rt < 4; ++rt) an[rt] = *(const bf16x8_t*)(ap + (size_t)(rt * 16) * lda2 + kn);
      #pragma unroll
      for (int rt = 0; rt < 4; ++rt)
        #pragma unroll
        for (int ct = 0; ct < 4; ++ct)
          acc[rt][ct] = __builtin_amdgcn_mfma_f32_16x16x32_bf16(a[rt], b[ct], acc[rt][ct], 0, 0, 0);
      #pragma unroll
      for (int rt = 0; rt < 4; ++rt) a[rt] = an[rt];
    }
  }
  // ---- epilogue ----
  const int cb = lr * 4;
  float bv[4] = {0.f, 0.f, 0.f, 0.f};
  if (bias) {
    #pragma unroll
    for (int j = 0; j < 4; ++j) bv[j] = bf2f(bias[n0 + cb + j]);
  }
  float* cs = &Cs[wave][0];
  float a1s[4] = {0.f, 0.f, 0.f, 0.f}, a2s[4] = {0.f, 0.f, 0.f, 0.f};
  #pragma unroll
  for (int round = 0; round < 2; ++round) {
    #pragma unroll
    for (int rt2 = 0; rt2 < 2; ++rt2) {
      int rt = round * 2 + rt2;
      #pragma unroll
      for (int ct = 0; ct < 4; ++ct)
        #pragma unroll
        for (int r = 0; r < 4; ++r) {
          float v = acc[rt][ct][r];
          if constexpr (RN) v += bias ? bf2f(bias[n0 + ct * 16 + lr]) : 0.0f;
          cs[(rt2 * 16 + quad * 4 + r) * 68 + ct * 16 + lr] = v;
        }
    }
    if constexpr (RN) { if (threadIdx.x < 32) SSq[threadIdx.x] = 0.0f; }
    __syncthreads();
    if constexpr (RN) {
      #pragma unroll
      for (int it = 0; it < 8; ++it) {
        int Lr = it * 4 + quad;
        float4 v = *(const float4*)(cs + Lr * 68 + cb);
        float ss = v.x*v.x + v.y*v.y + v.z*v.z + v.w*v.w;
        #pragma unroll
        for (int off = 1; off < 16; off <<= 1) ss += __shfl_xor(ss, off, 64);
        if (lr == 0) atomicAdd(&SSq[Lr], ss);
      }
      __syncthreads();
      #pragma unroll
      for (int it = 0; it < 8; ++it) {
        int Lr = it * 4 + quad;
        float inv = 1.0f / fmaxf(sqrtf(SSq[Lr]), 1e-12f);
        float4 v = *(const float4*)(cs + Lr * 68 + cb);
        float r0 = v.x * inv, r1 = v.y * inv, r2 = v.z * inv, r3 = v.w * inv;
        a1s[0] += r0; a1s[1] += r1; a1s[2] += r2; a1s[3] += r3;
        a2s[0] += r0*r0; a2s[1] += r1*r1; a2s[2] += r2*r2; a2s[3] += r3*r3;
        size_t ob = (size_t)(m0 + round * 32 + Lr) * ldOut + n0 + cb;
        uint2 o; o.x = pack2(r0, r1); o.y = pack2(r2, r3);
        *(uint2*)(out + ob) = o;
      }
    } else {
      #pragma unroll
      for (int it = 0; it < 8; ++it) {
        int Lr = it * 4 + quad;
        float4 v = *(const float4*)(cs + Lr * 68 + cb);
        int grow = m0 + round * 32 + Lr;
        size_t ob = (size_t)grow * ldOut + n0 + cb;
        float r0 = v.x + bv[0], r1 = v.y + bv[1], r2 = v.z + bv[2], r3 = v.w + bv[3];
        if (addend) {
          uint2 ad = *(const uint2*)(addend + ob);
          r0 += u2f_lo(ad.x); r1 += u2f_hi(ad.x);
          r2 += u2f_lo(ad.y); r3 += u2f_hi(ad.y);
        }
        uint2 o; o.x = pack2(r0, r1); o.y = pack2(r2, r3);
        *(uint2*)(out + ob) = o;
      }
    }
    __syncthreads();
  }
  if constexpr (RN) {
    const int g = m0 >> 9;
    #pragma unroll
    for (int k = 0; k < 4; ++k) {
      atomicAdd(&m1[g*C_ + n0 + cb + k], a1s[k]);
      atomicAdd(&m2[g*C_ + n0 + cb + k], a2s[k]);
    }
  }
}

// GraphNorm + GELU + residual. m1/m2 hold SUMS over 512 nodes.
__global__ __launch_bounds__(256) void gn_gelu_add(const ushort* __restrict__ h,
    const ushort* res,
    const float* __restrict__ m1, const float* __restrict__ m2,
    const ushort* __restrict__ gw, const ushort* __restrict__ gb, const ushort* __restrict__ ga,
    ushort* out)
{
  size_t b4 = ((size_t)blockIdx.x * 256 + threadIdx.x) * 4;
  int c = (int)(b4 & (C_ - 1));
  int n = (int)(b4 >> 8);
  int g = n >> 9;
  uint2 hv = *(const uint2*)(h + b4);
  uint2 rv = *(const uint2*)(res + b4);
  float hh[4] = {u2f_lo(hv.x), u2f_hi(hv.x), u2f_lo(hv.y), u2f_hi(hv.y)};
  float rr[4] = {u2f_lo(rv.x), u2f_hi(rv.x), u2f_lo(rv.y), u2f_hi(rv.y)};
  float oo[4];
  #pragma unroll
  for (int j = 0; j < 4; ++j) {
    int cc = c + j;
    float a  = bf2f(ga[cc]);
    float mm = m1[g*C_ + cc] * (1.0f / 512.0f);
    float q2 = m2[g*C_ + cc] * (1.0f / 512.0f);
    float var = q2 - a * (2.0f - a) * mm * mm;
    float xo = hh[j] - a * mm;
    float y = bf2f(gw[cc]) * xo * rsqrtf(var + 1e-5f) + bf2f(gb[cc]);
    oo[j] = gelu_f(y) + rr[j];
  }
  uint2 ov; ov.x = pack2(oo[0], oo[1]); ov.y = pack2(oo[2], oo[3]);
  *(uint2*)(out + b4) = ov;
}

// ---------------------------------------------------------------------------
// MFMA attention (R9, best measured): one block (512 thr) per (graph, head).
#define KS_P 72
#define VT_P 520
#define PW_P 40
__global__ __launch_bounds__(512, 2) void attn_kernel(ushort* __restrict__ qkv)
{
  __shared__ ushort Ks[NP_ * KS_P];
  __shared__ ushort Vt[64 * VT_P];
  __shared__ ushort Pw[8][16 * PW_P];
  const int bid = blockIdx.x;
  const int g = bid >> 2, h = bid & 3;
  const int tid = threadIdx.x, lane = tid & 63, wave = tid >> 6;
  const int lr = lane & 15, quad = lane >> 4;
  const size_t base = (size_t)g * NP_ * C3_;
  const int qoff = h * 64, koff = C_ + h * 64, voff = 2 * C_ + h * 64;
  for (int idx = tid; idx < NP_ * 64; idx += 512) {
    int j = idx >> 6, c = idx & 63;
    const ushort* row = qkv + base + (size_t)j * C3_;
    Ks[j * KS_P + c] = row[koff + c];
    Vt[c * VT_P + j] = row[voff + c];
  }
  __syncthreads();
  ushort* pw = &Pw[wave][0];
  const int q0 = wave * 64;
  for (int qt = 0; qt < 4; ++qt) {
    const int qr = q0 + qt * 16;
    const ushort* qp = qkv + base + (size_t)(qr + lr) * C3_ + qoff + quad * 8;
    bf16x8_t qa0 = *(const bf16x8_t*)(qp);
    bf16x8_t qa1 = *(const bf16x8_t*)(qp + 32);
    f32x4_t s[32];
    #pragma unroll
    for (int t = 0; t < 32; ++t) {
      const ushort* kp = Ks + (size_t)(t * 16 + lr) * KS_P + quad * 8;
      bf16x8_t b0 = *(const bf16x8_t*)(kp);
      bf16x8_t b1 = *(const bf16x8_t*)(kp + 32);
      f32x4_t a = (f32x4_t){0.f, 0.f, 0.f, 0.f};
      a = __builtin_amdgcn_mfma_f32_16x16x32_bf16(qa0, b0, a, 0, 0, 0);
      a = __builtin_amdgcn_mfma_f32_16x16x32_bf16(qa1, b1, a, 0, 0, 0);
      s[t] = a;
    }
    float invv[4];
    #pragma unroll
    for (int r = 0; r < 4; ++r) {
      float m = s[0][r];
      #pragma unroll
      for (int t = 1; t < 32; ++t) m = fmaxf(m, s[t][r]);
      #pragma unroll
      for (int off = 8; off; off >>= 1) m = fmaxf(m, __shfl_xor(m, off, 64));
      float sm = 0.0f;
      #pragma unroll
      for (int t = 0; t < 32; ++t) {
        float e = __expf((s[t][r] - m) * 0.125f);
        s[t][r] = e; sm += e;
      }
      #pragma unroll
      for (int off = 8; off; off >>= 1) sm += __shfl_xor(sm, off, 64);
      invv[r] = 1.0f / sm;
    }
    f32x4_t o[4];
    #pragma unroll
    for (int t = 0; t < 4; ++t) o[t] = (f32x4_t){0.f, 0.f, 0.f, 0.f};
    for (int kc = 0; kc < 16; ++kc) {
      #pragma unroll
      for (int half = 0; half < 2; ++half) {
        int t = kc * 2 + half;
        #pragma unroll
        for (int r = 0; r < 4; ++r)
          pw[(quad * 4 + r) * PW_P + half * 16 + lr] = f2bf(s[t][r] * invv[r]);
      }
      __threadfence_block();
      bf16x8_t pa = *(const bf16x8_t*)(pw + lr * PW_P + quad * 8);
      #pragma unroll
      for (int nt = 0; nt < 4; ++nt) {
        const ushort* vp = Vt + (size_t)(nt * 16 + lr) * VT_P + kc * 32 + quad * 8;
        bf16x8_t b = *(const bf16x8_t*)(vp);
        o[nt] = __builtin_amdgcn_mfma_f32_16x16x32_bf16(pa, b, o[nt], 0, 0, 0);
      }
    }
    #pragma unroll
    for (int nt = 0; nt < 4; ++nt)
      #pragma unroll
      for (int r = 0; r < 4; ++r)
        qkv[base + (size_t)(qr + quad * 4 + r) * C3_ + koff + nt * 16 + lr] =
            f2bf(o[nt][r]);
  }
}

// ---------------------------------------------------------------------------
// Graph-LN partials: st2[g][sl] = (sum, sumsq) for 64-row slice. No atomics.
__global__ __launch_bounds__(256) void ln_part(const ushort* __restrict__ x2, float* __restrict__ st2)
{
  __shared__ float a1[4], a2[4];
  const int g = blockIdx.x, sl = blockIdx.y;
  const int tid = threadIdx.x, lane = tid & 63, wave = tid >> 6;
  const ushort* p = x2 + ((size_t)g * NP_ + sl * 64) * C_;
  float s = 0.0f, q = 0.0f;
  for (int i = tid; i < 64 * C_; i += 256) { float v = bf2f(p[i]); s += v; q += v * v; }
  s = wredsum(s); q = wredsum(q);
  if (lane == 0) { a1[wave] = s; a2[wave] = q; }
  __syncthreads();
  if (tid == 0) {
    st2[(g * 8 + sl) * 2]     = a1[0] + a1[1] + a1[2] + a1[3];
    st2[(g * 8 + sl) * 2 + 1] = a2[0] + a2[1] + a2[2] + a2[3];
  }
}

// ln_gelu with inline finalize (block spans 4 nodes of one graph).
__global__ __launch_bounds__(256) void ln_gelu(const ushort* __restrict__ x2, const float* __restrict__ st2,
    const ushort* __restrict__ lw, const ushort* __restrict__ lb, ushort* __restrict__ x3)
{
  __shared__ float musd[2];
  size_t b4 = ((size_t)blockIdx.x * 256 + threadIdx.x) * 4;
  int c = (int)(b4 & (C_ - 1));
  int g = (int)(b4 >> 17);             // 2^17 elements per graph
  if (threadIdx.x == 0) {
    float S = 0.0f, Q = 0.0f;
    #pragma unroll
    for (int sl = 0; sl < 8; ++sl) {
      S += st2[(g * 8 + sl) * 2];
      Q += st2[(g * 8 + sl) * 2 + 1];
    }
    float mu = S * (1.0f / (NP_ * C_));
    float var = Q * (1.0f / (NP_ * C_)) - mu * mu;
    musd[0] = mu; musd[1] = rsqrtf(var + 1e-5f);
  }
  __syncthreads();
  float mu = musd[0], rs = musd[1];
  uint2 v = *(const uint2*)(x2 + b4);
  float vv[4] = {u2f_lo(v.x), u2f_hi(v.x), u2f_lo(v.y), u2f_hi(v.y)};
  float oo[4];
  #pragma unroll
  for (int j = 0; j < 4; ++j) {
    int cc = c + j;
    float y = (vv[j] - mu) * rs * bf2f(lw[cc]) + bf2f(lb[cc]);
    oo[j] = gelu_f(y);
  }
  uint2 ov; ov.x = pack2(oo[0], oo[1]); ov.y = pack2(oo[2], oo[3]);
  *(uint2*)(x3 + b4) = ov;
}

// ---------------------------------------------------------------------------
// Pool: per-slice partials (grid 128x8) then fused combine+projection.
__global__ __launch_bounds__(256) void pool_part(const ushort* __restrict__ x3,
    float* __restrict__ psum, float* __restrict__ pmax)
{
  const int g = blockIdx.x, sl = blockIdx.y, c = threadIdx.x;
  const ushort* p = x3 + ((size_t)g * NP_ + sl * 64) * C_ + c;
  float s = 0.0f, mx = -3.0e38f;
  #pragma unroll 4
  for (int r = 0; r < 64; ++r) {
    float v = bf2f(p[(size_t)r * C_]);
    s += v; mx = fmaxf(mx, v);
  }
  psum[((size_t)g * 8 + sl) * C_ + c] = s;
  pmax[((size_t)g * 8 + sl) * C_ + c] = mx;
}

// combine partials -> pooled[768] in LDS -> out = pooled @ W^T + b
__global__ __launch_bounds__(256) void final_gemm(const float* __restrict__ psum,
    const float* __restrict__ pmax,
    const ushort* __restrict__ W, const ushort* __restrict__ b, void* __restrict__ out,
    const uint* __restrict__ flag)
{
  __shared__ float pl[C3_];
  const int g = blockIdx.x, c = threadIdx.x;
  float s = 0.0f, mx = -3.0e38f;
  #pragma unroll
  for (int sl = 0; sl < 8; ++sl) {
    s += psum[((size_t)g * 8 + sl) * C_ + c];
    mx = fmaxf(mx, pmax[((size_t)g * 8 + sl) * C_ + c]);
  }
  pl[c] = s * (1.0f / 512.0f);
  pl[C_ + c] = mx;
  pl[2 * C_ + c] = s;
  __syncthreads();
  float acc = bf2f(b[c]);
  const ushort* wr = W + (size_t)c * C3_;
  for (int k = 0; k < C3_; k += 2) {
    uint wv = *(const uint*)(wr + k);
    acc += pl[k] * u2f_lo(wv) + pl[k + 1] * u2f_hi(wv);
  }
  if (*flag) ((float*)out)[g * C_ + c] = acc;
  else       ((ushort*)out)[g * C_ + c] = f2bf(acc);
}

// ---------------------------------------------------------------------------
extern "C" void kernel_launch(void* const* d_in, const int* in_sizes, int n_in,
                              void* d_out, int out_size, void* d_ws, size_t ws_size,
                              hipStream_t stream)
{
  const int* ei   = (const int*)d_in[1];
  const int* srcp = ei;
  const int* dstp = ei + E_TOT;

  const size_t NC = (size_t)N_TOT * C_;                        // 16,777,216
  const size_t NEEDED = (4ull << 20) + 4 * NC * sizeof(ushort); // 132 MB
  if (ws_size < NEEDED) return;

  unsigned char* wsb = (unsigned char*)d_ws;
  uint*   deg    = (uint*)wsb;                          // 256 KB
  float*  mbuf   = (float*)(wsb + (256u << 10));        // 4 layers x (m1,m2) = 1 MB
  float*  st2    = (float*)(wsb + (1280u << 10));       // ln partials 8 KB
  uint*   flag   = (uint*)(wsb + (1288u << 10));
  ushort* PB     = (ushort*)(wsb + (1792u << 10));      // param pool bf16 ~1.9MB
  ushort* S0     = (ushort*)(wsb + (4u << 20));         // x1
  ushort* S1     = S0 + NC;
  ushort* S2     = S1 + NC;
  ushort* S3     = S2 + NC;
  ushort* qkvb   = S1;                                  // [N][768] overlay
  ushort* XB     = S3;                                  // x bf16 (lower 16MB of S3)
  unsigned char* s3hi = (unsigned char*)(S3 + (size_t)N_TOT * DIN_);
  int*  csr    = (int*)s3hi;                            // 2 MB
  uint* rowptr = (uint*)(s3hi + (2u << 20));            // 256 KB
  uint* cursor = (uint*)(s3hi + (2u << 20) + (256u << 10));
  float* psum  = (float*)S2;                            // pool partials (S2 dead then)
  float* pmax  = psum + (size_t)B_GR * 8 * C_;

  // ---- dtype probe + import ----
  probe_dtype<<<1, 1, 0, stream>>>((const uint*)d_in[10], flag);
  CvtArgs ca;
  ca.s[0]  = { d_in[3],  O_L0LW };  ca.s[1]  = { d_in[4],  O_L0LB };
  ca.s[2]  = { d_in[5],  O_L0RW };  ca.s[3]  = { d_in[6],  O_L0RES };
  ca.s[4]  = { d_in[7],  O_LWL  };  ca.s[5]  = { d_in[8],  O_LBL  };
  ca.s[6]  = { d_in[9],  O_LWR  };  ca.s[7]  = { d_in[10], O_GNW  };
  ca.s[8]  = { d_in[11], O_GNB  };  ca.s[9]  = { d_in[12], O_GNA  };
  ca.s[10] = { d_in[13], O_AIW  };  ca.s[11] = { d_in[14], O_AIB  };
  ca.s[12] = { d_in[15], O_AOW  };  ca.s[13] = { d_in[16], O_AOB  };
  ca.s[14] = { d_in[17], O_LNW  };  ca.s[15] = { d_in[18], O_LNB  };
  ca.s[16] = { d_in[19], O_PLW  };  ca.s[17] = { d_in[20], O_PLB  };
  ca.s[18] = { nullptr,  TOTALP };
  cvt_params<<<(TOTALP + 255) / 256, 256, 0, stream>>>(ca, PB, flag);
  cvt_flat<<<(N_TOT * DIN_) / 256, 256, 0, stream>>>(d_in[0], XB, flag);

  // ---- zero deg + all per-layer moment buffers in one pass each ----
  hipMemsetAsync(deg, 0, N_TOT * sizeof(uint), stream);
  hipMemsetAsync(mbuf, 0, (1u << 20), stream);           // 4 layers m1+m2

  // ---- degree + CSR build ----
  deg_count<<<E_TOT / 256, 256, 0, stream>>>(dstp, deg);
  scan_deg<<<B_GR, 512, 0, stream>>>(deg, rowptr, cursor);
  scatter_edges<<<E_TOT / 256, 256, 0, stream>>>(srcp, dstp, cursor, csr);

  const size_t MSZ = (size_t)B_GR * C_;   // one moment buffer
  // ---- layer 0 (DIN=128 -> C=256) ----
  {
    float* m1 = mbuf;            // layer 0
    float* m2 = mbuf + MSZ * 4;
    sage_agg_csr<DIN_><<<N_TOT / 4, 256, 0, stream>>>(XB, csr, rowptr, deg, S1);
    gemm_mfma<true, true><<<dim3(N_TOT / 64, 1), 256, 0, stream>>>(
        S1, DIN_, PB + O_L0LW, XB, DIN_, PB + O_L0RW, PB + O_L0LB, nullptr, S2, DIN_, C_, m1, m2);
    gemm_mfma<false, false><<<dim3(N_TOT / 64, 1), 256, 0, stream>>>(
        XB, DIN_, PB + O_L0RES, nullptr, 0, nullptr, nullptr, nullptr, S0, DIN_, C_, nullptr, nullptr);
    gn_gelu_add<<<(N_TOT * C_) / 1024, 256, 0, stream>>>(S2, S0, m1, m2,
        PB + O_GNW, PB + O_GNB, PB + O_GNA, S0);
  }

  // ---- layers 1..3 (C -> C) ----
  for (int i = 0; i < 3; ++i) {
    float* m1 = mbuf + MSZ * (i + 1);
    float* m2 = mbuf + MSZ * 4 + MSZ * (i + 1);
    sage_agg_csr<C_><<<N_TOT / 4, 256, 0, stream>>>(S0, csr, rowptr, deg, S1);
    gemm_mfma<true, true><<<dim3(N_TOT / 64, 1), 256, 0, stream>>>(
        S1, C_, PB + O_LWL + (size_t)i * C_ * C_, S0, C_, PB + O_LWR + (size_t)i * C_ * C_,
        PB + O_LBL + i * C_, nullptr, S2, C_, C_, m1, m2);
    gn_gelu_add<<<(N_TOT * C_) / 1024, 256, 0, stream>>>(S2, S0, m1, m2,
        PB + O_GNW + (i + 1) * C_, PB + O_GNB + (i + 1) * C_, PB + O_GNA + (i + 1) * C_, S0);
  }

  // ---- attention ----
  gemm_mfma<false, false><<<dim3(N_TOT / 64, 3), 256, 0, stream>>>(
      S0, C_, PB + O_AIW, nullptr, 0, nullptr, PB + O_AIB, nullptr, qkvb, C_, C3_, nullptr, nullptr);
  attn_kernel<<<B_GR * H_, 512, 0, stream>>>(qkvb);
  // o lives in the K columns (ld 768)
  gemm_mfma<false, false><<<dim3(N_TOT / 64, 1), 256, 0, stream>>>(
      qkvb + C_, C3_, PB + O_AOW, nullptr, 0, nullptr, PB + O_AOB, S0, S0, C_, C_, nullptr, nullptr);

  // ---- graph LayerNorm + gelu ----
  ln_part<<<dim3(B_GR, 8), 256, 0, stream>>>(S0, st2);
  ln_gelu<<<(N_TOT * C_) / 1024, 256, 0, stream>>>(S0, st2, PB + O_LNW, PB + O_LNB, S1);

  // ---- pool + projection ----
  pool_part<<<dim3(B_GR, 8), 256, 0, stream>>>(S1, psum, pmax);
  final_gemm<<<B_GR, 256, 0, stream>>>(psum, pmax, PB + O_PLW, PB + O_PLB, d_out, flag);
}

// Round 13
// 1025.513 us; speedup vs baseline: 1.4310x; 1.1548x over previous
//
#include <hip/hip_runtime.h>

// ---------------------------------------------------------------------------
// GraphSAGE GNN forward, MI355X round 13: GEMM v4 — HBM-efficiency fix.
// R12 counters showed the GEMM at exactly bytes/BW with 1 TB/s effective and
// 2x write amplification (scattered 64-128B accesses). v4 stages A via LDS
// with full-row coalesced loads and stores full 512B rows from a block-wide
// LDS epilogue (unioned with the A buffer; 33.8KB, still 4 blocks/CU).
// ---------------------------------------------------------------------------

#define N_TOT   65536
#define B_GR    128
#define NP_     512
#define E_TOT   524288
#define EPG     4096
#define DIN_    128
#define C_      256
#define C3_     768
#define H_      4

typedef unsigned int uint;
typedef unsigned short ushort;

// param pool element offsets (ushorts)
#define O_L0LW  0u
#define O_L0LB  32768u
#define O_L0RW  33024u
#define O_L0RES 65792u
#define O_LWL   98560u
#define O_LBL   295168u
#define O_LWR   295936u
#define O_GNW   492544u
#define O_GNB   493568u
#define O_GNA   494592u
#define O_AIW   495616u
#define O_AIB   692224u
#define O_AOW   692992u
#define O_AOB   758528u
#define O_LNW   758784u
#define O_LNB   759040u
#define O_PLW   759296u
#define O_PLB   955904u
#define TOTALP  956160u

typedef __attribute__((ext_vector_type(8))) short bf16x8_t;
typedef __attribute__((ext_vector_type(4))) float f32x4_t;

__device__ __forceinline__ float bf2f(ushort u){ union{uint i; float f;} v; v.i = ((uint)u) << 16; return v.f; }
__device__ __forceinline__ ushort f2bf(float f){
  union{float f; uint u;} v; v.f = f;
  uint u = v.u;
  u += 0x7fffu + ((u >> 16) & 1u);   // RNE
  return (ushort)(u >> 16);
}
__device__ __forceinline__ uint pack2(float a, float b){ return (uint)f2bf(a) | ((uint)f2bf(b) << 16); }
__device__ __forceinline__ float u2f_lo(uint u){ union{uint i; float f;} v; v.i = u << 16; return v.f; }
__device__ __forceinline__ float u2f_hi(uint u){ union{uint i; float f;} v; v.i = u & 0xffff0000u; return v.f; }
__device__ __forceinline__ float gelu_f(float x){ return 0.5f * x * (1.0f + erff(x * 0.70710678118654752440f)); }
__device__ __forceinline__ float wredsum(float v){
  #pragma unroll
  for (int off = 32; off; off >>= 1) v += __shfl_xor(v, off, 64);
  return v;
}

// ---------------------------------------------------------------------------
// dtype probe: gn_w[0]==1.0. f32 -> 0x3F800000 ; bf16 pair -> 0x3F803F80
__global__ void probe_dtype(const uint* __restrict__ gnw_raw, uint* __restrict__ flag){
  if (threadIdx.x == 0 && blockIdx.x == 0)
    *flag = (gnw_raw[0] == 0x3F800000u) ? 1u : 0u;   // 1 = f32 inputs
}

struct Seg { const void* p; uint ofs; };
struct CvtArgs { Seg s[19]; };

__global__ __launch_bounds__(256) void cvt_params(CvtArgs a, ushort* __restrict__ pb,
                                                  const uint* __restrict__ flag){
  uint gi = blockIdx.x * 256u + threadIdx.x;
  if (gi >= TOTALP) return;
  int lo = 0;
  #pragma unroll
  for (int s = 1; s < 18; ++s) if (gi >= a.s[s].ofs) lo = s;
  uint rel = gi - a.s[lo].ofs;
  pb[gi] = (*flag) ? f2bf(((const float*)a.s[lo].p)[rel]) : ((const ushort*)a.s[lo].p)[rel];
}

__global__ __launch_bounds__(256) void cvt_flat(const void* __restrict__ in, ushort* __restrict__ out,
                                                const uint* __restrict__ flag){
  uint i = blockIdx.x * 256u + threadIdx.x;
  out[i] = (*flag) ? f2bf(((const float*)in)[i]) : ((const ushort*)in)[i];
}

// ---------------------------------------------------------------------------
__global__ void deg_count(const int* __restrict__ dst, uint* __restrict__ deg){
  int e = blockIdx.x * 256 + threadIdx.x;
  atomicAdd(&deg[dst[e]], 1u);
}

// per-graph exclusive scan of deg (512 nodes) -> rowptr/cursor
__global__ __launch_bounds__(512) void scan_deg(const uint* __restrict__ deg,
    uint* __restrict__ rowptr, uint* __restrict__ cursor)
{
  __shared__ uint s[512];
  const int g = blockIdx.x, tid = threadIdx.x;
  uint v = deg[g * NP_ + tid];
  s[tid] = v;
  __syncthreads();
  #pragma unroll
  for (int off = 1; off < 512; off <<= 1) {
    uint t = (tid >= off) ? s[tid - off] : 0u;
    __syncthreads();
    s[tid] += t;
    __syncthreads();
  }
  uint p = g * EPG + (s[tid] - v);
  rowptr[g * NP_ + tid] = p;
  cursor[g * NP_ + tid] = p;
}

__global__ void scatter_edges(const int* __restrict__ src, const int* __restrict__ dst,
    uint* __restrict__ cursor, int* __restrict__ csr)
{
  int e = blockIdx.x * 256 + threadIdx.x;
  uint p = atomicAdd(&cursor[dst[e]], 1u);
  csr[p] = src[e];
}

// ---------------------------------------------------------------------------
// CSR mean-aggregation: one wave per node. Lane owns D/64 channels.
template<int D>
__global__ __launch_bounds__(256) void sage_agg_csr(const ushort* __restrict__ X,
    const int* __restrict__ csr, const uint* __restrict__ rowptr,
    const uint* __restrict__ deg, ushort* __restrict__ agg)
{
  constexpr int CPL = D / 64;
  const int tid = threadIdx.x, lane = tid & 63, wave = tid >> 6;
  const int n = blockIdx.x * 4 + wave;
  const uint start = rowptr[n];
  const uint dg = deg[n];
  const int co = lane * CPL;
  float acc[CPL];
  #pragma unroll
  for (int k = 0; k < CPL; ++k) acc[k] = 0.0f;

  auto addrow = [&](int s) {
    const ushort* r = X + (size_t)s * D + co;
    if constexpr (CPL == 2) {
      uint u = *(const uint*)r;
      acc[0] += u2f_lo(u); acc[1] += u2f_hi(u);
    } else {
      uint2 u = *(const uint2*)r;
      acc[0] += u2f_lo(u.x); acc[1] += u2f_hi(u.x);
      acc[2] += u2f_lo(u.y); acc[3] += u2f_hi(u.y);
    }
  };

  uint j = 0;
  for (; j + 4 <= dg; j += 4) {
    int s0 = csr[start + j],     s1 = csr[start + j + 1];
    int s2 = csr[start + j + 2], s3 = csr[start + j + 3];
    addrow(s0); addrow(s1); addrow(s2); addrow(s3);
  }
  for (; j < dg; ++j) addrow(csr[start + j]);

  float inv = 1.0f / (float)(dg < 1u ? 1u : dg);
  ushort* op = agg + (size_t)n * D + co;
  if constexpr (CPL == 2) {
    *(uint*)op = pack2(acc[0] * inv, acc[1] * inv);
  } else {
    uint2 o; o.x = pack2(acc[0] * inv, acc[1] * inv);
    o.y = pack2(acc[2] * inv, acc[3] * inv);
    *(uint2*)op = o;
  }
}

// ---------------------------------------------------------------------------
// MFMA GEMM v4: 64x256 block, 4 waves, wave = 64x64 (16 tiles).
// A staged via LDS (full-row coalesced HBM reads, pitch K+8); W direct (L2).
// Epilogue: block-wide 32x260 f32 staging -> full 512B-row stores.
// RN=true: fused row-L2-normalize (full-wave reduce) + GraphNorm moments.
#define CS_P 260
template<bool DUAL, bool RN>
__global__ __launch_bounds__(256, 4) void gemm_mfma(
    const ushort* __restrict__ A1, int lda1, const ushort* __restrict__ W1,
    const ushort* __restrict__ A2, int lda2, const ushort* __restrict__ W2,
    const ushort* __restrict__ bias, const ushort* addend,   // addend may alias out
    ushort* out, int K, int ldOut,
    float* __restrict__ m1, float* __restrict__ m2)
{
  __shared__ __align__(16) unsigned char smem[34816];   // max(64*(K+8)*2, 32*260*4)
  ushort* As = (ushort*)smem;
  float*  Cs = (float*)smem;
  const int tid = threadIdx.x;
  const int lane = tid & 63, wave = tid >> 6;
  const int lr = lane & 15, quad = lane >> 4;
  const int m0 = blockIdx.x * 64;
  const int n0b = blockIdx.y * 256;
  const int n0 = n0b + wave * 64;
  const int KP = K + 8;
  f32x4_t acc[4][4];
  #pragma unroll
  for (int rt = 0; rt < 4; ++rt)
    #pragma unroll
    for (int ct = 0; ct < 4; ++ct) acc[rt][ct] = (f32x4_t){0.f, 0.f, 0.f, 0.f};

  const int lpr = K >> 3;          // threads per row (16B each)
  const int rpp = 256 / lpr;       // rows per staging pass
  const int passes = 64 / rpp;     // K/32
  const int tr = tid / lpr, tc = (tid % lpr) * 8;

  // ---- stream 1 ----
  for (int p = 0; p < passes; ++p) {
    int row = p * rpp + tr;
    *(bf16x8_t*)(As + row * KP + tc) =
        *(const bf16x8_t*)(A1 + (size_t)(m0 + row) * lda1 + tc);
  }
  __syncthreads();
  {
    const ushort* wp = W1 + (size_t)(n0 + lr) * K + quad * 8;
    for (int kb = 0; kb < K; kb += 32) {
      bf16x8_t a[4], b[4];
      #pragma unroll
      for (int ct = 0; ct < 4; ++ct) b[ct] = *(const bf16x8_t*)(wp + (size_t)(ct * 16) * K + kb);
      #pragma unroll
      for (int rt = 0; rt < 4; ++rt)
        a[rt] = *(const bf16x8_t*)(As + (rt * 16 + lr) * KP + kb + quad * 8);
      #pragma unroll
      for (int rt = 0; rt < 4; ++rt)
        #pragma unroll
        for (int ct = 0; ct < 4; ++ct)
          acc[rt][ct] = __builtin_amdgcn_mfma_f32_16x16x32_bf16(a[rt], b[ct], acc[rt][ct], 0, 0, 0);
    }
  }
  __syncthreads();
  // ---- stream 2 ----
  if constexpr (DUAL) {
    for (int p = 0; p < passes; ++p) {
      int row = p * rpp + tr;
      *(bf16x8_t*)(As + row * KP + tc) =
          *(const bf16x8_t*)(A2 + (size_t)(m0 + row) * lda2 + tc);
    }
    __syncthreads();
    const ushort* wp = W2 + (size_t)(n0 + lr) * K + quad * 8;
    for (int kb = 0; kb < K; kb += 32) {
      bf16x8_t a[4], b[4];
      #pragma unroll
      for (int ct = 0; ct < 4; ++ct) b[ct] = *(const bf16x8_t*)(wp + (size_t)(ct * 16) * K + kb);
      #pragma unroll
      for (int rt = 0; rt < 4; ++rt)
        a[rt] = *(const bf16x8_t*)(As + (rt * 16 + lr) * KP + kb + quad * 8);
      #pragma unroll
      for (int rt = 0; rt < 4; ++rt)
        #pragma unroll
        for (int ct = 0; ct < 4; ++ct)
          acc[rt][ct] = __builtin_amdgcn_mfma_f32_16x16x32_bf16(a[rt], b[ct], acc[rt][ct], 0, 0, 0);
    }
    __syncthreads();
  }

  // ---- epilogue: block-wide staging, full-row stores ----
  // staging bias (RN adds bias pre-normalize; cols owned by this wave)
  float bvs[4];
  if (RN && bias) {
    #pragma unroll
    for (int ct = 0; ct < 4; ++ct) bvs[ct] = bf2f(bias[n0 + ct * 16 + lr]);
  }
  // store-path bias (non-RN; cols = lane*4)
  float bvL[4] = {0.f, 0.f, 0.f, 0.f};
  if (!RN && bias) {
    #pragma unroll
    for (int j = 0; j < 4; ++j) bvL[j] = bf2f(bias[n0b + lane * 4 + j]);
  }
  float a1s[4] = {0.f, 0.f, 0.f, 0.f}, a2s[4] = {0.f, 0.f, 0.f, 0.f};
  #pragma unroll
  for (int round = 0; round < 2; ++round) {
    #pragma unroll
    for (int rt2 = 0; rt2 < 2; ++rt2) {
      int rt = round * 2 + rt2;
      #pragma unroll
      for (int ct = 0; ct < 4; ++ct)
        #pragma unroll
        for (int r = 0; r < 4; ++r) {
          float v = acc[rt][ct][r];
          if constexpr (RN) v += bias ? bvs[ct] : 0.0f;
          Cs[(rt2 * 16 + quad * 4 + r) * CS_P + wave * 64 + ct * 16 + lr] = v;
        }
    }
    __syncthreads();
    #pragma unroll
    for (int it = 0; it < 8; ++it) {
      int row = wave * 8 + it;                 // 0..31
      float4 v = *(const float4*)(Cs + row * CS_P + lane * 4);
      int grow = m0 + round * 32 + row;
      size_t ob = (size_t)grow * ldOut + n0b + lane * 4;
      if constexpr (RN) {
        float ss = v.x*v.x + v.y*v.y + v.z*v.z + v.w*v.w;
        ss = wredsum(ss);                      // full row (64 lanes x 4 cols)
        float inv = 1.0f / fmaxf(sqrtf(ss), 1e-12f);
        float r0 = v.x * inv, r1 = v.y * inv, r2 = v.z * inv, r3 = v.w * inv;
        a1s[0] += r0; a1s[1] += r1; a1s[2] += r2; a1s[3] += r3;
        a2s[0] += r0*r0; a2s[1] += r1*r1; a2s[2] += r2*r2; a2s[3] += r3*r3;
        uint2 o; o.x = pack2(r0, r1); o.y = pack2(r2, r3);
        *(uint2*)(out + ob) = o;
      } else {
        float r0 = v.x + bvL[0], r1 = v.y + bvL[1], r2 = v.z + bvL[2], r3 = v.w + bvL[3];
        if (addend) {
          uint2 ad = *(const uint2*)(addend + ob);
          r0 += u2f_lo(ad.x); r1 += u2f_hi(ad.x);
          r2 += u2f_lo(ad.y); r3 += u2f_hi(ad.y);
        }
        uint2 o; o.x = pack2(r0, r1); o.y = pack2(r2, r3);
        *(uint2*)(out + ob) = o;
      }
    }
    __syncthreads();
  }
  if constexpr (RN) {
    const int g = m0 >> 9;
    #pragma unroll
    for (int k = 0; k < 4; ++k) {
      atomicAdd(&m1[g*C_ + lane * 4 + k], a1s[k]);
      atomicAdd(&m2[g*C_ + lane * 4 + k], a2s[k]);
    }
  }
}

// GraphNorm + GELU + residual. m1/m2 hold SUMS over 512 nodes.
__global__ __launch_bounds__(256) void gn_gelu_add(const ushort* __restrict__ h,
    const ushort* res,
    const float* __restrict__ m1, const float* __restrict__ m2,
    const ushort* __restrict__ gw, const ushort* __restrict__ gb, const ushort* __restrict__ ga,
    ushort* out)
{
  size_t b4 = ((size_t)blockIdx.x * 256 + threadIdx.x) * 4;
  int c = (int)(b4 & (C_ - 1));
  int n = (int)(b4 >> 8);
  int g = n >> 9;
  uint2 hv = *(const uint2*)(h + b4);
  uint2 rv = *(const uint2*)(res + b4);
  float hh[4] = {u2f_lo(hv.x), u2f_hi(hv.x), u2f_lo(hv.y), u2f_hi(hv.y)};
  float rr[4] = {u2f_lo(rv.x), u2f_hi(rv.x), u2f_lo(rv.y), u2f_hi(rv.y)};
  float oo[4];
  #pragma unroll
  for (int j = 0; j < 4; ++j) {
    int cc = c + j;
    float a  = bf2f(ga[cc]);
    float mm = m1[g*C_ + cc] * (1.0f / 512.0f);
    float q2 = m2[g*C_ + cc] * (1.0f / 512.0f);
    float var = q2 - a * (2.0f - a) * mm * mm;
    float xo = hh[j] - a * mm;
    float y = bf2f(gw[cc]) * xo * rsqrtf(var + 1e-5f) + bf2f(gb[cc]);
    oo[j] = gelu_f(y) + rr[j];
  }
  uint2 ov; ov.x = pack2(oo[0], oo[1]); ov.y = pack2(oo[2], oo[3]);
  *(uint2*)(out + b4) = ov;
}

// ---------------------------------------------------------------------------
// MFMA attention (best measured): one block (512 thr) per (graph, head).
#define KS_P 72
#define VT_P 520
#define PW_P 40
__global__ __launch_bounds__(512, 2) void attn_kernel(ushort* __restrict__ qkv)
{
  __shared__ ushort Ks[NP_ * KS_P];
  __shared__ ushort Vt[64 * VT_P];
  __shared__ ushort Pw[8][16 * PW_P];
  const int bid = blockIdx.x;
  const int g = bid >> 2, h = bid & 3;
  const int tid = threadIdx.x, lane = tid & 63, wave = tid >> 6;
  const int lr = lane & 15, quad = lane >> 4;
  const size_t base = (size_t)g * NP_ * C3_;
  const int qoff = h * 64, koff = C_ + h * 64, voff = 2 * C_ + h * 64;
  for (int idx = tid; idx < NP_ * 64; idx += 512) {
    int j = idx >> 6, c = idx & 63;
    const ushort* row = qkv + base + (size_t)j * C3_;
    Ks[j * KS_P + c] = row[koff + c];
    Vt[c * VT_P + j] = row[voff + c];
  }
  __syncthreads();
  ushort* pw = &Pw[wave][0];
  const int q0 = wave * 64;
  for (int qt = 0; qt < 4; ++qt) {
    const int qr = q0 + qt * 16;
    const ushort* qp = qkv + base + (size_t)(qr + lr) * C3_ + qoff + quad * 8;
    bf16x8_t qa0 = *(const bf16x8_t*)(qp);
    bf16x8_t qa1 = *(const bf16x8_t*)(qp + 32);
    f32x4_t s[32];
    #pragma unroll
    for (int t = 0; t < 32; ++t) {
      const ushort* kp = Ks + (size_t)(t * 16 + lr) * KS_P + quad * 8;
      bf16x8_t b0 = *(const bf16x8_t*)(kp);
      bf16x8_t b1 = *(const bf16x8_t*)(kp + 32);
      f32x4_t a = (f32x4_t){0.f, 0.f, 0.f, 0.f};
      a = __builtin_amdgcn_mfma_f32_16x16x32_bf16(qa0, b0, a, 0, 0, 0);
      a = __builtin_amdgcn_mfma_f32_16x16x32_bf16(qa1, b1, a, 0, 0, 0);
      s[t] = a;
    }
    float invv[4];
    #pragma unroll
    for (int r = 0; r < 4; ++r) {
      float m = s[0][r];
      #pragma unroll
      for (int t = 1; t < 32; ++t) m = fmaxf(m, s[t][r]);
      #pragma unroll
      for (int off = 8; off; off >>= 1) m = fmaxf(m, __shfl_xor(m, off, 64));
      float sm = 0.0f;
      #pragma unroll
      for (int t = 0; t < 32; ++t) {
        float e = __expf((s[t][r] - m) * 0.125f);
        s[t][r] = e; sm += e;
      }
      #pragma unroll
      for (int off = 8; off; off >>= 1) sm += __shfl_xor(sm, off, 64);
      invv[r] = 1.0f / sm;
    }
    f32x4_t o[4];
    #pragma unroll
    for (int t = 0; t < 4; ++t) o[t] = (f32x4_t){0.f, 0.f, 0.f, 0.f};
    for (int kc = 0; kc < 16; ++kc) {
      #pragma unroll
      for (int half = 0; half < 2; ++half) {
        int t = kc * 2 + half;
        #pragma unroll
        for (int r = 0; r < 4; ++r)
          pw[(quad * 4 + r) * PW_P + half * 16 + lr] = f2bf(s[t][r] * invv[r]);
      }
      __threadfence_block();
      bf16x8_t pa = *(const bf16x8_t*)(pw + lr * PW_P + quad * 8);
      #pragma unroll
      for (int nt = 0; nt < 4; ++nt) {
        const ushort* vp = Vt + (size_t)(nt * 16 + lr) * VT_P + kc * 32 + quad * 8;
        bf16x8_t b = *(const bf16x8_t*)(vp);
        o[nt] = __builtin_amdgcn_mfma_f32_16x16x32_bf16(pa, b, o[nt], 0, 0, 0);
      }
    }
    #pragma unroll
    for (int nt = 0; nt < 4; ++nt)
      #pragma unroll
      for (int r = 0; r < 4; ++r)
        qkv[base + (size_t)(qr + quad * 4 + r) * C3_ + koff + nt * 16 + lr] =
            f2bf(o[nt][r]);
  }
}

// ---------------------------------------------------------------------------
// Graph-LN partials: st2[g][sl] = (sum, sumsq) for 64-row slice. No atomics.
__global__ __launch_bounds__(256) void ln_part(const ushort* __restrict__ x2, float* __restrict__ st2)
{
  __shared__ float a1[4], a2[4];
  const int g = blockIdx.x, sl = blockIdx.y;
  const int tid = threadIdx.x, lane = tid & 63, wave = tid >> 6;
  const ushort* p = x2 + ((size_t)g * NP_ + sl * 64) * C_;
  float s = 0.0f, q = 0.0f;
  for (int i = tid; i < 64 * C_; i += 256) { float v = bf2f(p[i]); s += v; q += v * v; }
  s = wredsum(s); q = wredsum(q);
  if (lane == 0) { a1[wave] = s; a2[wave] = q; }
  __syncthreads();
  if (tid == 0) {
    st2[(g * 8 + sl) * 2]     = a1[0] + a1[1] + a1[2] + a1[3];
    st2[(g * 8 + sl) * 2 + 1] = a2[0] + a2[1] + a2[2] + a2[3];
  }
}

// ln_gelu with inline finalize (block spans 4 nodes of one graph).
__global__ __launch_bounds__(256) void ln_gelu(const ushort* __restrict__ x2, const float* __restrict__ st2,
    const ushort* __restrict__ lw, const ushort* __restrict__ lb, ushort* __restrict__ x3)
{
  __shared__ float musd[2];
  size_t b4 = ((size_t)blockIdx.x * 256 + threadIdx.x) * 4;
  int c = (int)(b4 & (C_ - 1));
  int g = (int)(b4 >> 17);             // 2^17 elements per graph
  if (threadIdx.x == 0) {
    float S = 0.0f, Q = 0.0f;
    #pragma unroll
    for (int sl = 0; sl < 8; ++sl) {
      S += st2[(g * 8 + sl) * 2];
      Q += st2[(g * 8 + sl) * 2 + 1];
    }
    float mu = S * (1.0f / (NP_ * C_));
    float var = Q * (1.0f / (NP_ * C_)) - mu * mu;
    musd[0] = mu; musd[1] = rsqrtf(var + 1e-5f);
  }
  __syncthreads();
  float mu = musd[0], rs = musd[1];
  uint2 v = *(const uint2*)(x2 + b4);
  float vv[4] = {u2f_lo(v.x), u2f_hi(v.x), u2f_lo(v.y), u2f_hi(v.y)};
  float oo[4];
  #pragma unroll
  for (int j = 0; j < 4; ++j) {
    int cc = c + j;
    float y = (vv[j] - mu) * rs * bf2f(lw[cc]) + bf2f(lb[cc]);
    oo[j] = gelu_f(y);
  }
  uint2 ov; ov.x = pack2(oo[0], oo[1]); ov.y = pack2(oo[2], oo[3]);
  *(uint2*)(x3 + b4) = ov;
}

// ---------------------------------------------------------------------------
// Pool: per-slice partials (grid 128x8) then fused combine+projection.
__global__ __launch_bounds__(256) void pool_part(const ushort* __restrict__ x3,
    float* __restrict__ psum, float* __restrict__ pmax)
{
  const int g = blockIdx.x, sl = blockIdx.y, c = threadIdx.x;
  const ushort* p = x3 + ((size_t)g * NP_ + sl * 64) * C_ + c;
  float s = 0.0f, mx = -3.0e38f;
  #pragma unroll 4
  for (int r = 0; r < 64; ++r) {
    float v = bf2f(p[(size_t)r * C_]);
    s += v; mx = fmaxf(mx, v);
  }
  psum[((size_t)g * 8 + sl) * C_ + c] = s;
  pmax[((size_t)g * 8 + sl) * C_ + c] = mx;
}

// combine partials -> pooled[768] in LDS -> out = pooled @ W^T + b
__global__ __launch_bounds__(256) void final_gemm(const float* __restrict__ psum,
    const float* __restrict__ pmax,
    const ushort* __restrict__ W, const ushort* __restrict__ b, void* __restrict__ out,
    const uint* __restrict__ flag)
{
  __shared__ float pl[C3_];
  const int g = blockIdx.x, c = threadIdx.x;
  float s = 0.0f, mx = -3.0e38f;
  #pragma unroll
  for (int sl = 0; sl < 8; ++sl) {
    s += psum[((size_t)g * 8 + sl) * C_ + c];
    mx = fmaxf(mx, pmax[((size_t)g * 8 + sl) * C_ + c]);
  }
  pl[c] = s * (1.0f / 512.0f);
  pl[C_ + c] = mx;
  pl[2 * C_ + c] = s;
  __syncthreads();
  float acc = bf2f(b[c]);
  const ushort* wr = W + (size_t)c * C3_;
  for (int k = 0; k < C3_; k += 2) {
    uint wv = *(const uint*)(wr + k);
    acc += pl[k] * u2f_lo(wv) + pl[k + 1] * u2f_hi(wv);
  }
  if (*flag) ((float*)out)[g * C_ + c] = acc;
  else       ((ushort*)out)[g * C_ + c] = f2bf(acc);
}

// ---------------------------------------------------------------------------
extern "C" void kernel_launch(void* const* d_in, const int* in_sizes, int n_in,
                              void* d_out, int out_size, void* d_ws, size_t ws_size,
                              hipStream_t stream)
{
  const int* ei   = (const int*)d_in[1];
  const int* srcp = ei;
  const int* dstp = ei + E_TOT;

  const size_t NC = (size_t)N_TOT * C_;                        // 16,777,216
  const size_t NEEDED = (4ull << 20) + 4 * NC * sizeof(ushort); // 132 MB
  if (ws_size < NEEDED) return;

  unsigned char* wsb = (unsigned char*)d_ws;
  uint*   deg    = (uint*)wsb;                          // 256 KB
  float*  mbuf   = (float*)(wsb + (256u << 10));        // 4 layers x (m1,m2) = 1 MB
  float*  st2    = (float*)(wsb + (1280u << 10));       // ln partials 8 KB
  uint*   flag   = (uint*)(wsb + (1288u << 10));
  ushort* PB     = (ushort*)(wsb + (1792u << 10));      // param pool bf16 ~1.9MB
  ushort* S0     = (ushort*)(wsb + (4u << 20));         // x1
  ushort* S1     = S0 + NC;
  ushort* S2     = S1 + NC;
  ushort* S3     = S2 + NC;
  ushort* qkvb   = S1;                                  // [N][768] overlay
  ushort* XB     = S3;                                  // x bf16 (lower 16MB of S3)
  unsigned char* s3hi = (unsigned char*)(S3 + (size_t)N_TOT * DIN_);
  int*  csr    = (int*)s3hi;                            // 2 MB
  uint* rowptr = (uint*)(s3hi + (2u << 20));            // 256 KB
  uint* cursor = (uint*)(s3hi + (2u << 20) + (256u << 10));
  float* psum  = (float*)S2;                            // pool partials (S2 dead then)
  float* pmax  = psum + (size_t)B_GR * 8 * C_;

  // ---- dtype probe + import ----
  probe_dtype<<<1, 1, 0, stream>>>((const uint*)d_in[10], flag);
  CvtArgs ca;
  ca.s[0]  = { d_in[3],  O_L0LW };  ca.s[1]  = { d_in[4],  O_L0LB };
  ca.s[2]  = { d_in[5],  O_L0RW };  ca.s[3]  = { d_in[6],  O_L0RES };
  ca.s[4]  = { d_in[7],  O_LWL  };  ca.s[5]  = { d_in[8],  O_LBL  };
  ca.s[6]  = { d_in[9],  O_LWR  };  ca.s[7]  = { d_in[10], O_GNW  };
  ca.s[8]  = { d_in[11], O_GNB  };  ca.s[9]  = { d_in[12], O_GNA  };
  ca.s[10] = { d_in[13], O_AIW  };  ca.s[11] = { d_in[14], O_AIB  };
  ca.s[12] = { d_in[15], O_AOW  };  ca.s[13] = { d_in[16], O_AOB  };
  ca.s[14] = { d_in[17], O_LNW  };  ca.s[15] = { d_in[18], O_LNB  };
  ca.s[16] = { d_in[19], O_PLW  };  ca.s[17] = { d_in[20], O_PLB  };
  ca.s[18] = { nullptr,  TOTALP };
  cvt_params<<<(TOTALP + 255) / 256, 256, 0, stream>>>(ca, PB, flag);
  cvt_flat<<<(N_TOT * DIN_) / 256, 256, 0, stream>>>(d_in[0], XB, flag);

  // ---- zero deg + all per-layer moment buffers ----
  hipMemsetAsync(deg, 0, N_TOT * sizeof(uint), stream);
  hipMemsetAsync(mbuf, 0, (1u << 20), stream);

  // ---- degree + CSR build ----
  deg_count<<<E_TOT / 256, 256, 0, stream>>>(dstp, deg);
  scan_deg<<<B_GR, 512, 0, stream>>>(deg, rowptr, cursor);
  scatter_edges<<<E_TOT / 256, 256, 0, stream>>>(srcp, dstp, cursor, csr);

  const size_t MSZ = (size_t)B_GR * C_;
  // ---- layer 0 (DIN=128 -> C=256) ----
  {
    float* m1 = mbuf;
    float* m2 = mbuf + MSZ * 4;
    sage_agg_csr<DIN_><<<N_TOT / 4, 256, 0, stream>>>(XB, csr, rowptr, deg, S1);
    gemm_mfma<true, true><<<dim3(N_TOT / 64, 1), 256, 0, stream>>>(
        S1, DIN_, PB + O_L0LW, XB, DIN_, PB + O_L0RW, PB + O_L0LB, nullptr, S2, DIN_, C_, m1, m2);
    gemm_mfma<false, false><<<dim3(N_TOT / 64, 1), 256, 0, stream>>>(
        XB, DIN_, PB + O_L0RES, nullptr, 0, nullptr, nullptr, nullptr, S0, DIN_, C_, nullptr, nullptr);
    gn_gelu_add<<<(N_TOT * C_) / 1024, 256, 0, stream>>>(S2, S0, m1, m2,
        PB + O_GNW, PB + O_GNB, PB + O_GNA, S0);
  }

  // ---- layers 1..3 (C -> C) ----
  for (int i = 0; i < 3; ++i) {
    float* m1 = mbuf + MSZ * (i + 1);
    float* m2 = mbuf + MSZ * 4 + MSZ * (i + 1);
    sage_agg_csr<C_><<<N_TOT / 4, 256, 0, stream>>>(S0, csr, rowptr, deg, S1);
    gemm_mfma<true, true><<<dim3(N_TOT / 64, 1), 256, 0, stream>>>(
        S1, C_, PB + O_LWL + (size_t)i * C_ * C_, S0, C_, PB + O_LWR + (size_t)i * C_ * C_,
        PB + O_LBL + i * C_, nullptr, S2, C_, C_, m1, m2);
    gn_gelu_add<<<(N_TOT * C_) / 1024, 256, 0, stream>>>(S2, S0, m1, m2,
        PB + O_GNW + (i + 1) * C_, PB + O_GNB + (i + 1) * C_, PB + O_GNA + (i + 1) * C_, S0);
  }

  // ---- attention ----
  gemm_mfma<false, false><<<dim3(N_TOT / 64, 3), 256, 0, stream>>>(
      S0, C_, PB + O_AIW, nullptr, 0, nullptr, PB + O_AIB, nullptr, qkvb, C_, C3_, nullptr, nullptr);
  attn_kernel<<<B_GR * H_, 512, 0, stream>>>(qkvb);
  // o lives in the K columns (ld 768)
  gemm_mfma<false, false><<<dim3(N_TOT / 64, 1), 256, 0, stream>>>(
      qkvb + C_, C3_, PB + O_AOW, nullptr, 0, nullptr, PB + O_AOB, S0, S0, C_, C_, nullptr, nullptr);

  // ---- graph LayerNorm + gelu ----
  ln_part<<<dim3(B_GR, 8), 256, 0, stream>>>(S0, st2);
  ln_gelu<<<(N_TOT * C_) / 1024, 256, 0, stream>>>(S0, st2, PB + O_LNW, PB + O_LNB, S1);

  // ---- pool + projection ----
  pool_part<<<dim3(B_GR, 8), 256, 0, stream>>>(S1, psum, pmax);
  final_gemm<<<B_GR, 256, 0, stream>>>(psum, pmax, PB + O_PLW, PB + O_PLB, d_out, flag);
}

// Round 14
// 1021.233 us; speedup vs baseline: 1.4370x; 1.0042x over previous
//
#include <hip/hip_runtime.h>

// ---------------------------------------------------------------------------
// GraphSAGE GNN forward, MI355X round 14:
//  - attn Vt XOR-swizzle (kills the 1.1e7 LDS bank conflicts: colliding lanes
//    differ in c by multiples of 8 -> key swizzle on c bits 3..5)
//  - graph-LN stats fused into out-proj GEMM epilogue (drops ln_part)
// ---------------------------------------------------------------------------

#define N_TOT   65536
#define B_GR    128
#define NP_     512
#define E_TOT   524288
#define EPG     4096
#define DIN_    128
#define C_      256
#define C3_     768
#define H_      4

typedef unsigned int uint;
typedef unsigned short ushort;

// param pool element offsets (ushorts)
#define O_L0LW  0u
#define O_L0LB  32768u
#define O_L0RW  33024u
#define O_L0RES 65792u
#define O_LWL   98560u
#define O_LBL   295168u
#define O_LWR   295936u
#define O_GNW   492544u
#define O_GNB   493568u
#define O_GNA   494592u
#define O_AIW   495616u
#define O_AIB   692224u
#define O_AOW   692992u
#define O_AOB   758528u
#define O_LNW   758784u
#define O_LNB   759040u
#define O_PLW   759296u
#define O_PLB   955904u
#define TOTALP  956160u

typedef __attribute__((ext_vector_type(8))) short bf16x8_t;
typedef __attribute__((ext_vector_type(4))) float f32x4_t;

__device__ __forceinline__ float bf2f(ushort u){ union{uint i; float f;} v; v.i = ((uint)u) << 16; return v.f; }
__device__ __forceinline__ ushort f2bf(float f){
  union{float f; uint u;} v; v.f = f;
  uint u = v.u;
  u += 0x7fffu + ((u >> 16) & 1u);   // RNE
  return (ushort)(u >> 16);
}
__device__ __forceinline__ uint pack2(float a, float b){ return (uint)f2bf(a) | ((uint)f2bf(b) << 16); }
__device__ __forceinline__ float u2f_lo(uint u){ union{uint i; float f;} v; v.i = u << 16; return v.f; }
__device__ __forceinline__ float u2f_hi(uint u){ union{uint i; float f;} v; v.i = u & 0xffff0000u; return v.f; }
__device__ __forceinline__ float gelu_f(float x){ return 0.5f * x * (1.0f + erff(x * 0.70710678118654752440f)); }
__device__ __forceinline__ float wredsum(float v){
  #pragma unroll
  for (int off = 32; off; off >>= 1) v += __shfl_xor(v, off, 64);
  return v;
}

// ---------------------------------------------------------------------------
// dtype probe: gn_w[0]==1.0. f32 -> 0x3F800000 ; bf16 pair -> 0x3F803F80
__global__ void probe_dtype(const uint* __restrict__ gnw_raw, uint* __restrict__ flag){
  if (threadIdx.x == 0 && blockIdx.x == 0)
    *flag = (gnw_raw[0] == 0x3F800000u) ? 1u : 0u;   // 1 = f32 inputs
}

struct Seg { const void* p; uint ofs; };
struct CvtArgs { Seg s[19]; };

__global__ __launch_bounds__(256) void cvt_params(CvtArgs a, ushort* __restrict__ pb,
                                                  const uint* __restrict__ flag){
  uint gi = blockIdx.x * 256u + threadIdx.x;
  if (gi >= TOTALP) return;
  int lo = 0;
  #pragma unroll
  for (int s = 1; s < 18; ++s) if (gi >= a.s[s].ofs) lo = s;
  uint rel = gi - a.s[lo].ofs;
  pb[gi] = (*flag) ? f2bf(((const float*)a.s[lo].p)[rel]) : ((const ushort*)a.s[lo].p)[rel];
}

__global__ __launch_bounds__(256) void cvt_flat(const void* __restrict__ in, ushort* __restrict__ out,
                                                const uint* __restrict__ flag){
  uint i = blockIdx.x * 256u + threadIdx.x;
  out[i] = (*flag) ? f2bf(((const float*)in)[i]) : ((const ushort*)in)[i];
}

// ---------------------------------------------------------------------------
__global__ void deg_count(const int* __restrict__ dst, uint* __restrict__ deg){
  int e = blockIdx.x * 256 + threadIdx.x;
  atomicAdd(&deg[dst[e]], 1u);
}

__global__ __launch_bounds__(512) void scan_deg(const uint* __restrict__ deg,
    uint* __restrict__ rowptr, uint* __restrict__ cursor)
{
  __shared__ uint s[512];
  const int g = blockIdx.x, tid = threadIdx.x;
  uint v = deg[g * NP_ + tid];
  s[tid] = v;
  __syncthreads();
  #pragma unroll
  for (int off = 1; off < 512; off <<= 1) {
    uint t = (tid >= off) ? s[tid - off] : 0u;
    __syncthreads();
    s[tid] += t;
    __syncthreads();
  }
  uint p = g * EPG + (s[tid] - v);
  rowptr[g * NP_ + tid] = p;
  cursor[g * NP_ + tid] = p;
}

__global__ void scatter_edges(const int* __restrict__ src, const int* __restrict__ dst,
    uint* __restrict__ cursor, int* __restrict__ csr)
{
  int e = blockIdx.x * 256 + threadIdx.x;
  uint p = atomicAdd(&cursor[dst[e]], 1u);
  csr[p] = src[e];
}

// ---------------------------------------------------------------------------
// CSR mean-aggregation: one wave per node. Lane owns D/64 channels.
template<int D>
__global__ __launch_bounds__(256) void sage_agg_csr(const ushort* __restrict__ X,
    const int* __restrict__ csr, const uint* __restrict__ rowptr,
    const uint* __restrict__ deg, ushort* __restrict__ agg)
{
  constexpr int CPL = D / 64;
  const int tid = threadIdx.x, lane = tid & 63, wave = tid >> 6;
  const int n = blockIdx.x * 4 + wave;
  const uint start = rowptr[n];
  const uint dg = deg[n];
  const int co = lane * CPL;
  float acc[CPL];
  #pragma unroll
  for (int k = 0; k < CPL; ++k) acc[k] = 0.0f;

  auto addrow = [&](int s) {
    const ushort* r = X + (size_t)s * D + co;
    if constexpr (CPL == 2) {
      uint u = *(const uint*)r;
      acc[0] += u2f_lo(u); acc[1] += u2f_hi(u);
    } else {
      uint2 u = *(const uint2*)r;
      acc[0] += u2f_lo(u.x); acc[1] += u2f_hi(u.x);
      acc[2] += u2f_lo(u.y); acc[3] += u2f_hi(u.y);
    }
  };

  uint j = 0;
  for (; j + 4 <= dg; j += 4) {
    int s0 = csr[start + j],     s1 = csr[start + j + 1];
    int s2 = csr[start + j + 2], s3 = csr[start + j + 3];
    addrow(s0); addrow(s1); addrow(s2); addrow(s3);
  }
  for (; j < dg; ++j) addrow(csr[start + j]);

  float inv = 1.0f / (float)(dg < 1u ? 1u : dg);
  ushort* op = agg + (size_t)n * D + co;
  if constexpr (CPL == 2) {
    *(uint*)op = pack2(acc[0] * inv, acc[1] * inv);
  } else {
    uint2 o; o.x = pack2(acc[0] * inv, acc[1] * inv);
    o.y = pack2(acc[2] * inv, acc[3] * inv);
    *(uint2*)op = o;
  }
}

// ---------------------------------------------------------------------------
// MFMA GEMM v4: 64x256 block, 4 waves, wave = 64x64. A via LDS, W direct.
// Epilogue: block-wide 32x260 staging -> full 512B-row stores.
// RN: fused row-L2-normalize + GraphNorm moments. LN: fused graph-LN stats.
#define CS_P 260
template<bool DUAL, bool RN, bool LN>
__global__ __launch_bounds__(256, 4) void gemm_mfma(
    const ushort* __restrict__ A1, int lda1, const ushort* __restrict__ W1,
    const ushort* __restrict__ A2, int lda2, const ushort* __restrict__ W2,
    const ushort* __restrict__ bias, const ushort* addend,   // addend may alias out
    ushort* out, int K, int ldOut,
    float* __restrict__ m1, float* __restrict__ m2, float* __restrict__ st2)
{
  __shared__ __align__(16) unsigned char smem[34816];   // max(64*(K+8)*2, 32*260*4)
  ushort* As = (ushort*)smem;
  float*  Cs = (float*)smem;
  const int tid = threadIdx.x;
  const int lane = tid & 63, wave = tid >> 6;
  const int lr = lane & 15, quad = lane >> 4;
  const int m0 = blockIdx.x * 64;
  const int n0b = blockIdx.y * 256;
  const int n0 = n0b + wave * 64;
  const int KP = K + 8;
  f32x4_t acc[4][4];
  #pragma unroll
  for (int rt = 0; rt < 4; ++rt)
    #pragma unroll
    for (int ct = 0; ct < 4; ++ct) acc[rt][ct] = (f32x4_t){0.f, 0.f, 0.f, 0.f};

  const int lpr = K >> 3;
  const int rpp = 256 / lpr;
  const int passes = 64 / rpp;
  const int tr = tid / lpr, tc = (tid % lpr) * 8;

  // ---- stream 1 ----
  for (int p = 0; p < passes; ++p) {
    int row = p * rpp + tr;
    *(bf16x8_t*)(As + row * KP + tc) =
        *(const bf16x8_t*)(A1 + (size_t)(m0 + row) * lda1 + tc);
  }
  __syncthreads();
  {
    const ushort* wp = W1 + (size_t)(n0 + lr) * K + quad * 8;
    for (int kb = 0; kb < K; kb += 32) {
      bf16x8_t a[4], b[4];
      #pragma unroll
      for (int ct = 0; ct < 4; ++ct) b[ct] = *(const bf16x8_t*)(wp + (size_t)(ct * 16) * K + kb);
      #pragma unroll
      for (int rt = 0; rt < 4; ++rt)
        a[rt] = *(const bf16x8_t*)(As + (rt * 16 + lr) * KP + kb + quad * 8);
      #pragma unroll
      for (int rt = 0; rt < 4; ++rt)
        #pragma unroll
        for (int ct = 0; ct < 4; ++ct)
          acc[rt][ct] = __builtin_amdgcn_mfma_f32_16x16x32_bf16(a[rt], b[ct], acc[rt][ct], 0, 0, 0);
    }
  }
  __syncthreads();
  // ---- stream 2 ----
  if constexpr (DUAL) {
    for (int p = 0; p < passes; ++p) {
      int row = p * rpp + tr;
      *(bf16x8_t*)(As + row * KP + tc) =
          *(const bf16x8_t*)(A2 + (size_t)(m0 + row) * lda2 + tc);
    }
    __syncthreads();
    const ushort* wp = W2 + (size_t)(n0 + lr) * K + quad * 8;
    for (int kb = 0; kb < K; kb += 32) {
      bf16x8_t a[4], b[4];
      #pragma unroll
      for (int ct = 0; ct < 4; ++ct) b[ct] = *(const bf16x8_t*)(wp + (size_t)(ct * 16) * K + kb);
      #pragma unroll
      for (int rt = 0; rt < 4; ++rt)
        a[rt] = *(const bf16x8_t*)(As + (rt * 16 + lr) * KP + kb + quad * 8);
      #pragma unroll
      for (int rt = 0; rt < 4; ++rt)
        #pragma unroll
        for (int ct = 0; ct < 4; ++ct)
          acc[rt][ct] = __builtin_amdgcn_mfma_f32_16x16x32_bf16(a[rt], b[ct], acc[rt][ct], 0, 0, 0);
    }
    __syncthreads();
  }

  // ---- epilogue ----
  float bvs[4];
  if (RN && bias) {
    #pragma unroll
    for (int ct = 0; ct < 4; ++ct) bvs[ct] = bf2f(bias[n0 + ct * 16 + lr]);
  }
  float bvL[4] = {0.f, 0.f, 0.f, 0.f};
  if (!RN && bias) {
    #pragma unroll
    for (int j = 0; j < 4; ++j) bvL[j] = bf2f(bias[n0b + lane * 4 + j]);
  }
  float a1s[4] = {0.f, 0.f, 0.f, 0.f}, a2s[4] = {0.f, 0.f, 0.f, 0.f};
  float sln = 0.0f, qln = 0.0f;
  #pragma unroll
  for (int round = 0; round < 2; ++round) {
    #pragma unroll
    for (int rt2 = 0; rt2 < 2; ++rt2) {
      int rt = round * 2 + rt2;
      #pragma unroll
      for (int ct = 0; ct < 4; ++ct)
        #pragma unroll
        for (int r = 0; r < 4; ++r) {
          float v = acc[rt][ct][r];
          if constexpr (RN) v += bias ? bvs[ct] : 0.0f;
          Cs[(rt2 * 16 + quad * 4 + r) * CS_P + wave * 64 + ct * 16 + lr] = v;
        }
    }
    __syncthreads();
    #pragma unroll
    for (int it = 0; it < 8; ++it) {
      int row = wave * 8 + it;
      float4 v = *(const float4*)(Cs + row * CS_P + lane * 4);
      int grow = m0 + round * 32 + row;
      size_t ob = (size_t)grow * ldOut + n0b + lane * 4;
      if constexpr (RN) {
        float ss = v.x*v.x + v.y*v.y + v.z*v.z + v.w*v.w;
        ss = wredsum(ss);
        float inv = 1.0f / fmaxf(sqrtf(ss), 1e-12f);
        float r0 = v.x * inv, r1 = v.y * inv, r2 = v.z * inv, r3 = v.w * inv;
        a1s[0] += r0; a1s[1] += r1; a1s[2] += r2; a1s[3] += r3;
        a2s[0] += r0*r0; a2s[1] += r1*r1; a2s[2] += r2*r2; a2s[3] += r3*r3;
        uint2 o; o.x = pack2(r0, r1); o.y = pack2(r2, r3);
        *(uint2*)(out + ob) = o;
      } else {
        float r0 = v.x + bvL[0], r1 = v.y + bvL[1], r2 = v.z + bvL[2], r3 = v.w + bvL[3];
        if (addend) {
          uint2 ad = *(const uint2*)(addend + ob);
          r0 += u2f_lo(ad.x); r1 += u2f_hi(ad.x);
          r2 += u2f_lo(ad.y); r3 += u2f_hi(ad.y);
        }
        if constexpr (LN) {
          sln += r0 + r1 + r2 + r3;
          qln += r0*r0 + r1*r1 + r2*r2 + r3*r3;
        }
        uint2 o; o.x = pack2(r0, r1); o.y = pack2(r2, r3);
        *(uint2*)(out + ob) = o;
      }
    }
    __syncthreads();
  }
  if constexpr (RN) {
    const int g = m0 >> 9;
    #pragma unroll
    for (int k = 0; k < 4; ++k) {
      atomicAdd(&m1[g*C_ + lane * 4 + k], a1s[k]);
      atomicAdd(&m2[g*C_ + lane * 4 + k], a2s[k]);
    }
  }
  if constexpr (LN) {
    const int g = m0 >> 9;
    sln = wredsum(sln); qln = wredsum(qln);
    if (lane == 0) {
      atomicAdd(&st2[g * 2], sln);
      atomicAdd(&st2[g * 2 + 1], qln);
    }
  }
}

// GraphNorm + GELU + residual. m1/m2 hold SUMS over 512 nodes.
__global__ __launch_bounds__(256) void gn_gelu_add(const ushort* __restrict__ h,
    const ushort* res,
    const float* __restrict__ m1, const float* __restrict__ m2,
    const ushort* __restrict__ gw, const ushort* __restrict__ gb, const ushort* __restrict__ ga,
    ushort* out)
{
  size_t b4 = ((size_t)blockIdx.x * 256 + threadIdx.x) * 4;
  int c = (int)(b4 & (C_ - 1));
  int n = (int)(b4 >> 8);
  int g = n >> 9;
  uint2 hv = *(const uint2*)(h + b4);
  uint2 rv = *(const uint2*)(res + b4);
  float hh[4] = {u2f_lo(hv.x), u2f_hi(hv.x), u2f_lo(hv.y), u2f_hi(hv.y)};
  float rr[4] = {u2f_lo(rv.x), u2f_hi(rv.x), u2f_lo(rv.y), u2f_hi(rv.y)};
  float oo[4];
  #pragma unroll
  for (int j = 0; j < 4; ++j) {
    int cc = c + j;
    float a  = bf2f(ga[cc]);
    float mm = m1[g*C_ + cc] * (1.0f / 512.0f);
    float q2 = m2[g*C_ + cc] * (1.0f / 512.0f);
    float var = q2 - a * (2.0f - a) * mm * mm;
    float xo = hh[j] - a * mm;
    float y = bf2f(gw[cc]) * xo * rsqrtf(var + 1e-5f) + bf2f(gb[cc]);
    oo[j] = gelu_f(y) + rr[j];
  }
  uint2 ov; ov.x = pack2(oo[0], oo[1]); ov.y = pack2(oo[2], oo[3]);
  *(uint2*)(out + b4) = ov;
}

// ---------------------------------------------------------------------------
// MFMA attention: one block (512 thr) per (graph, head). Vt XOR-swizzled.
#define KS_P 72
#define VT_P 520
#define PW_P 40
__device__ __forceinline__ int vswz(int c){ return ((c >> 3) & 7) << 3; }
__global__ __launch_bounds__(512, 2) void attn_kernel(ushort* __restrict__ qkv)
{
  __shared__ ushort Ks[NP_ * KS_P];
  __shared__ ushort Vt[64 * VT_P];
  __shared__ ushort Pw[8][16 * PW_P];
  const int bid = blockIdx.x;
  const int g = bid >> 2, h = bid & 3;
  const int tid = threadIdx.x, lane = tid & 63, wave = tid >> 6;
  const int lr = lane & 15, quad = lane >> 4;
  const size_t base = (size_t)g * NP_ * C3_;
  const int qoff = h * 64, koff = C_ + h * 64, voff = 2 * C_ + h * 64;
  for (int idx = tid; idx < NP_ * 64; idx += 512) {
    int j = idx >> 6, c = idx & 63;
    const ushort* row = qkv + base + (size_t)j * C3_;
    Ks[j * KS_P + c] = row[koff + c];
    Vt[c * VT_P + (j ^ vswz(c))] = row[voff + c];
  }
  __syncthreads();
  ushort* pw = &Pw[wave][0];
  const int q0 = wave * 64;
  for (int qt = 0; qt < 4; ++qt) {
    const int qr = q0 + qt * 16;
    const ushort* qp = qkv + base + (size_t)(qr + lr) * C3_ + qoff + quad * 8;
    bf16x8_t qa0 = *(const bf16x8_t*)(qp);
    bf16x8_t qa1 = *(const bf16x8_t*)(qp + 32);
    f32x4_t s[32];
    #pragma unroll
    for (int t = 0; t < 32; ++t) {
      const ushort* kp = Ks + (size_t)(t * 16 + lr) * KS_P + quad * 8;
      bf16x8_t b0 = *(const bf16x8_t*)(kp);
      bf16x8_t b1 = *(const bf16x8_t*)(kp + 32);
      f32x4_t a = (f32x4_t){0.f, 0.f, 0.f, 0.f};
      a = __builtin_amdgcn_mfma_f32_16x16x32_bf16(qa0, b0, a, 0, 0, 0);
      a = __builtin_amdgcn_mfma_f32_16x16x32_bf16(qa1, b1, a, 0, 0, 0);
      s[t] = a;
    }
    float invv[4];
    #pragma unroll
    for (int r = 0; r < 4; ++r) {
      float m = s[0][r];
      #pragma unroll
      for (int t = 1; t < 32; ++t) m = fmaxf(m, s[t][r]);
      #pragma unroll
      for (int off = 8; off; off >>= 1) m = fmaxf(m, __shfl_xor(m, off, 64));
      float sm = 0.0f;
      #pragma unroll
      for (int t = 0; t < 32; ++t) {
        float e = __expf((s[t][r] - m) * 0.125f);
        s[t][r] = e; sm += e;
      }
      #pragma unroll
      for (int off = 8; off; off >>= 1) sm += __shfl_xor(sm, off, 64);
      invv[r] = 1.0f / sm;
    }
    f32x4_t o[4];
    #pragma unroll
    for (int t = 0; t < 4; ++t) o[t] = (f32x4_t){0.f, 0.f, 0.f, 0.f};
    for (int kc = 0; kc < 16; ++kc) {
      #pragma unroll
      for (int half = 0; half < 2; ++half) {
        int t = kc * 2 + half;
        #pragma unroll
        for (int r = 0; r < 4; ++r)
          pw[(quad * 4 + r) * PW_P + half * 16 + lr] = f2bf(s[t][r] * invv[r]);
      }
      __threadfence_block();
      bf16x8_t pa = *(const bf16x8_t*)(pw + lr * PW_P + quad * 8);
      #pragma unroll
      for (int nt = 0; nt < 4; ++nt) {
        int vrow = nt * 16 + lr;
        const ushort* vp = Vt + (size_t)vrow * VT_P + ((kc * 32 + quad * 8) ^ vswz(vrow));
        bf16x8_t b = *(const bf16x8_t*)(vp);
        o[nt] = __builtin_amdgcn_mfma_f32_16x16x32_bf16(pa, b, o[nt], 0, 0, 0);
      }
    }
    #pragma unroll
    for (int nt = 0; nt < 4; ++nt)
      #pragma unroll
      for (int r = 0; r < 4; ++r)
        qkv[base + (size_t)(qr + quad * 4 + r) * C3_ + koff + nt * 16 + lr] =
            f2bf(o[nt][r]);
  }
}

// ---------------------------------------------------------------------------
// ln_gelu: graph sums come from the out-proj GEMM's fused LN stats.
__global__ __launch_bounds__(256) void ln_gelu(const ushort* __restrict__ x2, const float* __restrict__ st2,
    const ushort* __restrict__ lw, const ushort* __restrict__ lb, ushort* __restrict__ x3)
{
  __shared__ float musd[2];
  size_t b4 = ((size_t)blockIdx.x * 256 + threadIdx.x) * 4;
  int c = (int)(b4 & (C_ - 1));
  int g = (int)(b4 >> 17);
  if (threadIdx.x == 0) {
    float S = st2[g * 2], Q = st2[g * 2 + 1];
    float mu = S * (1.0f / (NP_ * C_));
    float var = Q * (1.0f / (NP_ * C_)) - mu * mu;
    musd[0] = mu; musd[1] = rsqrtf(var + 1e-5f);
  }
  __syncthreads();
  float mu = musd[0], rs = musd[1];
  uint2 v = *(const uint2*)(x2 + b4);
  float vv[4] = {u2f_lo(v.x), u2f_hi(v.x), u2f_lo(v.y), u2f_hi(v.y)};
  float oo[4];
  #pragma unroll
  for (int j = 0; j < 4; ++j) {
    int cc = c + j;
    float y = (vv[j] - mu) * rs * bf2f(lw[cc]) + bf2f(lb[cc]);
    oo[j] = gelu_f(y);
  }
  uint2 ov; ov.x = pack2(oo[0], oo[1]); ov.y = pack2(oo[2], oo[3]);
  *(uint2*)(x3 + b4) = ov;
}

// ---------------------------------------------------------------------------
// Pool: per-slice partials (grid 128x8) then fused combine+projection.
__global__ __launch_bounds__(256) void pool_part(const ushort* __restrict__ x3,
    float* __restrict__ psum, float* __restrict__ pmax)
{
  const int g = blockIdx.x, sl = blockIdx.y, c = threadIdx.x;
  const ushort* p = x3 + ((size_t)g * NP_ + sl * 64) * C_ + c;
  float s = 0.0f, mx = -3.0e38f;
  #pragma unroll 4
  for (int r = 0; r < 64; ++r) {
    float v = bf2f(p[(size_t)r * C_]);
    s += v; mx = fmaxf(mx, v);
  }
  psum[((size_t)g * 8 + sl) * C_ + c] = s;
  pmax[((size_t)g * 8 + sl) * C_ + c] = mx;
}

__global__ __launch_bounds__(256) void final_gemm(const float* __restrict__ psum,
    const float* __restrict__ pmax,
    const ushort* __restrict__ W, const ushort* __restrict__ b, void* __restrict__ out,
    const uint* __restrict__ flag)
{
  __shared__ float pl[C3_];
  const int g = blockIdx.x, c = threadIdx.x;
  float s = 0.0f, mx = -3.0e38f;
  #pragma unroll
  for (int sl = 0; sl < 8; ++sl) {
    s += psum[((size_t)g * 8 + sl) * C_ + c];
    mx = fmaxf(mx, pmax[((size_t)g * 8 + sl) * C_ + c]);
  }
  pl[c] = s * (1.0f / 512.0f);
  pl[C_ + c] = mx;
  pl[2 * C_ + c] = s;
  __syncthreads();
  float acc = bf2f(b[c]);
  const ushort* wr = W + (size_t)c * C3_;
  for (int k = 0; k < C3_; k += 2) {
    uint wv = *(const uint*)(wr + k);
    acc += pl[k] * u2f_lo(wv) + pl[k + 1] * u2f_hi(wv);
  }
  if (*flag) ((float*)out)[g * C_ + c] = acc;
  else       ((ushort*)out)[g * C_ + c] = f2bf(acc);
}

// ---------------------------------------------------------------------------
extern "C" void kernel_launch(void* const* d_in, const int* in_sizes, int n_in,
                              void* d_out, int out_size, void* d_ws, size_t ws_size,
                              hipStream_t stream)
{
  const int* ei   = (const int*)d_in[1];
  const int* srcp = ei;
  const int* dstp = ei + E_TOT;

  const size_t NC = (size_t)N_TOT * C_;                        // 16,777,216
  const size_t NEEDED = (4ull << 20) + 4 * NC * sizeof(ushort); // 132 MB
  if (ws_size < NEEDED) return;

  unsigned char* wsb = (unsigned char*)d_ws;
  uint*   deg    = (uint*)wsb;                          // 256 KB
  float*  mbuf   = (float*)(wsb + (256u << 10));        // 4 layers x (m1,m2) = 1 MB
  float*  st2    = (float*)(wsb + (1280u << 10));       // ln sums 1 KB (zeroed w/ mbuf)
  uint*   flag   = (uint*)(wsb + (1288u << 10));
  ushort* PB     = (ushort*)(wsb + (1792u << 10));      // param pool bf16 ~1.9MB
  ushort* S0     = (ushort*)(wsb + (4u << 20));         // x1
  ushort* S1     = S0 + NC;
  ushort* S2     = S1 + NC;
  ushort* S3     = S2 + NC;
  ushort* qkvb   = S1;                                  // [N][768] overlay
  ushort* XB     = S3;                                  // x bf16 (lower 16MB of S3)
  unsigned char* s3hi = (unsigned char*)(S3 + (size_t)N_TOT * DIN_);
  int*  csr    = (int*)s3hi;                            // 2 MB
  uint* rowptr = (uint*)(s3hi + (2u << 20));            // 256 KB
  uint* cursor = (uint*)(s3hi + (2u << 20) + (256u << 10));
  float* psum  = (float*)S2;                            // pool partials (S2 dead then)
  float* pmax  = psum + (size_t)B_GR * 8 * C_;

  // ---- dtype probe + import ----
  probe_dtype<<<1, 1, 0, stream>>>((const uint*)d_in[10], flag);
  CvtArgs ca;
  ca.s[0]  = { d_in[3],  O_L0LW };  ca.s[1]  = { d_in[4],  O_L0LB };
  ca.s[2]  = { d_in[5],  O_L0RW };  ca.s[3]  = { d_in[6],  O_L0RES };
  ca.s[4]  = { d_in[7],  O_LWL  };  ca.s[5]  = { d_in[8],  O_LBL  };
  ca.s[6]  = { d_in[9],  O_LWR  };  ca.s[7]  = { d_in[10], O_GNW  };
  ca.s[8]  = { d_in[11], O_GNB  };  ca.s[9]  = { d_in[12], O_GNA  };
  ca.s[10] = { d_in[13], O_AIW  };  ca.s[11] = { d_in[14], O_AIB  };
  ca.s[12] = { d_in[15], O_AOW  };  ca.s[13] = { d_in[16], O_AOB  };
  ca.s[14] = { d_in[17], O_LNW  };  ca.s[15] = { d_in[18], O_LNB  };
  ca.s[16] = { d_in[19], O_PLW  };  ca.s[17] = { d_in[20], O_PLB  };
  ca.s[18] = { nullptr,  TOTALP };
  cvt_params<<<(TOTALP + 255) / 256, 256, 0, stream>>>(ca, PB, flag);
  cvt_flat<<<(N_TOT * DIN_) / 256, 256, 0, stream>>>(d_in[0], XB, flag);

  // ---- zero deg + moment buffers + ln sums (contiguous region) ----
  hipMemsetAsync(deg, 0, N_TOT * sizeof(uint), stream);
  hipMemsetAsync(mbuf, 0, (1u << 20) + 1024, stream);

  // ---- degree + CSR build ----
  deg_count<<<E_TOT / 256, 256, 0, stream>>>(dstp, deg);
  scan_deg<<<B_GR, 512, 0, stream>>>(deg, rowptr, cursor);
  scatter_edges<<<E_TOT / 256, 256, 0, stream>>>(srcp, dstp, cursor, csr);

  const size_t MSZ = (size_t)B_GR * C_;
  // ---- layer 0 (DIN=128 -> C=256) ----
  {
    float* m1 = mbuf;
    float* m2 = mbuf + MSZ * 4;
    sage_agg_csr<DIN_><<<N_TOT / 4, 256, 0, stream>>>(XB, csr, rowptr, deg, S1);
    gemm_mfma<true, true, false><<<dim3(N_TOT / 64, 1), 256, 0, stream>>>(
        S1, DIN_, PB + O_L0LW, XB, DIN_, PB + O_L0RW, PB + O_L0LB, nullptr, S2, DIN_, C_, m1, m2, nullptr);
    gemm_mfma<false, false, false><<<dim3(N_TOT / 64, 1), 256, 0, stream>>>(
        XB, DIN_, PB + O_L0RES, nullptr, 0, nullptr, nullptr, nullptr, S0, DIN_, C_, nullptr, nullptr, nullptr);
    gn_gelu_add<<<(N_TOT * C_) / 1024, 256, 0, stream>>>(S2, S0, m1, m2,
        PB + O_GNW, PB + O_GNB, PB + O_GNA, S0);
  }

  // ---- layers 1..3 (C -> C) ----
  for (int i = 0; i < 3; ++i) {
    float* m1 = mbuf + MSZ * (i + 1);
    float* m2 = mbuf + MSZ * 4 + MSZ * (i + 1);
    sage_agg_csr<C_><<<N_TOT / 4, 256, 0, stream>>>(S0, csr, rowptr, deg, S1);
    gemm_mfma<true, true, false><<<dim3(N_TOT / 64, 1), 256, 0, stream>>>(
        S1, C_, PB + O_LWL + (size_t)i * C_ * C_, S0, C_, PB + O_LWR + (size_t)i * C_ * C_,
        PB + O_LBL + i * C_, nullptr, S2, C_, C_, m1, m2, nullptr);
    gn_gelu_add<<<(N_TOT * C_) / 1024, 256, 0, stream>>>(S2, S0, m1, m2,
        PB + O_GNW + (i + 1) * C_, PB + O_GNB + (i + 1) * C_, PB + O_GNA + (i + 1) * C_, S0);
  }

  // ---- attention ----
  gemm_mfma<false, false, false><<<dim3(N_TOT / 64, 3), 256, 0, stream>>>(
      S0, C_, PB + O_AIW, nullptr, 0, nullptr, PB + O_AIB, nullptr, qkvb, C_, C3_, nullptr, nullptr, nullptr);
  attn_kernel<<<B_GR * H_, 512, 0, stream>>>(qkvb);
  // out-proj (+x1 residual) with fused graph-LN stats
  gemm_mfma<false, false, true><<<dim3(N_TOT / 64, 1), 256, 0, stream>>>(
      qkvb + C_, C3_, PB + O_AOW, nullptr, 0, nullptr, PB + O_AOB, S0, S0, C_, C_, nullptr, nullptr, st2);

  // ---- graph LayerNorm + gelu ----
  ln_gelu<<<(N_TOT * C_) / 1024, 256, 0, stream>>>(S0, st2, PB + O_LNW, PB + O_LNB, S1);

  // ---- pool + projection ----
  pool_part<<<dim3(B_GR, 8), 256, 0, stream>>>(S1, psum, pmax);
  final_gemm<<<B_GR, 256, 0, stream>>>(psum, pmax, PB + O_PLW, PB + O_PLB, d_out, flag);
}